// Round 10
// baseline (563.210 us; speedup 1.0000x reference)
//
#include <hip/hip_runtime.h>
#include <hip/hip_bf16.h>
#include <math.h>

#define T_   32
#define C_   128
#define GD_  64
#define KQK_ 192
#define NH_  4
#define HD_  32
#define C4_  512
#define HW_  1024

typedef unsigned short u16;
typedef __attribute__((ext_vector_type(8))) short short8;
typedef __attribute__((ext_vector_type(4))) short short4v;
typedef __attribute__((ext_vector_type(4))) float f32x4;
typedef __attribute__((ext_vector_type(4))) unsigned short u16x4;

// ---- ws layout ----
#define ACF_A 0
#define ACF_C 512
#define WQH 2048
#define WQL 26624
#define WKH 51200
#define WKL 75776
#define WVH 100352
#define WVL 116736
#define W1H 133120
#define W1L 198656
#define W2H 264192
#define W2L 329728
#define GSH 395264
#define GSL 403456
#define XT  411648           // [n][hi 4096 u16 | lo 4096 u16]; reused as X2 after attn
#define WS_NEED_BYTES (823296ull + 4096ull*8192ull*2ull)   // 67,932,160

// ---- Kernel A LDS (attn): pool ----
#define AX_H  0        // [64][200] u16 stride 400; rows 0-31 tile0, 32-63 tile1
#define AX_L  25600    // ends 51200
#define X2G(g) ((g)*8704)   // X2 overlay: group g of 16 rows, h row*272, l +4352; ends 34816
#define KSUM  51200    // 256 f32
#define ZDEN  52224    // 256 f32
#define STATS 53248    // 128 f32: mu1[64] rs1[64]
#define POOLA 53760    // x3 = 161280 <= 163840 -> 3 blocks/CU

// ---- Kernel B LDS (mlp) ----
#define BX2   0        // h [32][136]u16 rows stride 272 (8704), l at +8704; ends 17408
#define BHM   17408    // h [32][136] (8704), l at +8704; ends 34816
#define BST   34816    // 64 f32: mu2*rs2[32], rs2[32]
#define POOLB 35072    // x4 = 140288 <= 163840 -> 4 blocks/CU

__device__ __forceinline__ float b2f(u16 u) {
    unsigned int x = ((unsigned int)u) << 16;
    float f; __builtin_memcpy(&f, &x, 4); return f;
}
__device__ __forceinline__ u16 f2b(float f) {
    __hip_bfloat16 h = __float2bfloat16(f);
    u16 u; __builtin_memcpy(&u, &h, 2); return u;
}
__device__ __forceinline__ void split2(float v, u16& h, u16& l) {
    h = f2b(v); l = f2b(v - b2f(h));
}
__device__ __forceinline__ void splitfrag(const f32x4 v, short4v& h, short4v& l) {
    u16 hh[4], ll[4];
    #pragma unroll
    for (int r = 0; r < 4; ++r) { hh[r] = f2b(v[r]); ll[r] = f2b(v[r] - b2f(hh[r])); }
    h = (short4v){(short)hh[0],(short)hh[1],(short)hh[2],(short)hh[3]};
    l = (short4v){(short)ll[0],(short)ll[1],(short)ll[2],(short)ll[3]};
}

// Branch-free gelu (A&S 7.1.26 erf, max err 1.5e-7)
__device__ __forceinline__ float gelu_fast(float v) {
    float a  = fabsf(v) * 0.70710678118654752f;
    float t  = __builtin_amdgcn_rcpf(fmaf(a, 0.3275911f, 1.f));
    float p  = t*(0.254829592f + t*(-0.284496736f + t*(1.421413741f
             + t*(-1.453152027f + t*1.061405429f))));
    float P  = p * __expf(-a*a);
    float hv = 0.5f * v;
    return (v > 0.f) ? v - hv*P : hv*P;
}

__device__ __forceinline__ f32x4 mfma16(short4v a, short4v b, f32x4 c) {
#if __has_builtin(__builtin_amdgcn_mfma_f32_16x16x16bf16_1k)
    return __builtin_amdgcn_mfma_f32_16x16x16bf16_1k(a, b, c, 0, 0, 0);
#else
    asm("v_mfma_f32_16x16x16_bf16 %0, %1, %2, %0" : "+v"(c) : "v"(a), "v"(b));
    return c;
#endif
}

#define MFMA3(acc, ah, al, bh, bl)                                          \
    acc = __builtin_amdgcn_mfma_f32_16x16x32_bf16(ah, bh, acc, 0, 0, 0);    \
    acc = __builtin_amdgcn_mfma_f32_16x16x32_bf16(ah, bl, acc, 0, 0, 0);    \
    acc = __builtin_amdgcn_mfma_f32_16x16x32_bf16(al, bh, acc, 0, 0, 0);

#define MFMA3_16(acc, ah, al, bh, bl)                                       \
    acc = mfma16(ah, bh, acc);                                              \
    acc = mfma16(ah, bl, acc);                                              \
    acc = mfma16(al, bh, acc);

// ---- prep: split weights + guidance + a/cpl ----
__global__ void prep_weights(const float* __restrict__ Wq, const float* __restrict__ Wk,
                             const float* __restrict__ Wv, const float* __restrict__ W1,
                             const float* __restrict__ W2, const float* __restrict__ gui,
                             const float* __restrict__ g2, const float* __restrict__ be2,
                             const float* __restrict__ b1,
                             u16* __restrict__ wsp)
{
    int e = blockIdx.x * 256 + threadIdx.x;
    if (e >= 204800) {
        int n = e - 204800;
        if (n >= 512) return;
        float a = 0.f, c = 0.f;
        for (int k = 0; k < 128; ++k) {
            float w = W1[k*512 + n];
            a = fmaf(w, g2[k], a);
            c = fmaf(w, be2[k], c);
        }
        float* acf = (float*)wsp;
        acf[ACF_A + n] = a;
        acf[ACF_C + n] = c + b1[n];
        return;
    }
    if (e >= 196608) {
        int idx = e - 196608;
        float v = gui[idx];
        u16 hb = f2b(v);
        wsp[GSH + idx] = hb;
        wsp[GSL + idx] = f2b(v - b2f(hb));
        return;
    }
    const float* src; int e2, k, n, K; int oh, ol; int isW1 = 0;
    if (e < 24576)       { src = Wq; e2 = e;          k = e2 >> 7; n = e2 & 127; K = KQK_; oh = WQH; ol = WQL; }
    else if (e < 49152)  { src = Wk; e2 = e - 24576;  k = e2 >> 7; n = e2 & 127; K = KQK_; oh = WKH; ol = WKL; }
    else if (e < 65536)  { src = Wv; e2 = e - 49152;  k = e2 >> 7; n = e2 & 127; K = C_;   oh = WVH; ol = WVL; }
    else if (e < 131072) { src = W1; e2 = e - 65536;  k = e2 >> 9; n = e2 & 511; K = C_;   oh = W1H; ol = W1L; isW1 = 1; }
    else                 { src = W2; e2 = e - 131072; k = e2 >> 7; n = e2 & 127; K = C4_;  oh = W2H; ol = W2L; }
    float w = src[e2];
    if (isW1) w *= g2[k];
    u16 hb = f2b(w);
    wsp[oh + n * K + k] = hb;
    wsp[ol + n * K + k] = f2b(w - b2f(hb));
}

// ---- transpose x (unchanged) ----
__global__ __launch_bounds__(256) void transpose_x(const float* __restrict__ x, u16* __restrict__ wsp)
{
    __shared__ float tile[32][65];
    int bid = blockIdx.x;
    int hq = bid & 15, cq = (bid >> 4) & 3, t = (bid >> 6) & 31, b = bid >> 11;
    int c0 = cq * 32, hw0 = hq * 64;
    int tid = threadIdx.x;
    {
        int i = tid >> 3, j8 = (tid & 7) * 8;
        const float* src = x + ((size_t)((b*32 + t)*128 + c0 + i))*1024 + hw0 + j8;
        float4 v0 = *reinterpret_cast<const float4*>(src);
        float4 v1 = *reinterpret_cast<const float4*>(src + 4);
        tile[i][j8+0]=v0.x; tile[i][j8+1]=v0.y; tile[i][j8+2]=v0.z; tile[i][j8+3]=v0.w;
        tile[i][j8+4]=v1.x; tile[i][j8+5]=v1.y; tile[i][j8+6]=v1.z; tile[i][j8+7]=v1.w;
    }
    __syncthreads();
    {
        int jj = tid >> 2, c8 = (tid & 3) * 8;
        int n = b*1024 + hw0 + jj;
        u16 hh[8], ll[8];
        #pragma unroll
        for (int ii = 0; ii < 8; ++ii) {
            float v = tile[c8 + ii][jj];
            u16 hb = f2b(v);
            hh[ii] = hb; ll[ii] = f2b(v - b2f(hb));
        }
        u16* dh = wsp + XT + (size_t)n*8192 + t*128 + c0 + c8;
        u16* dl = dh + 4096;
        *reinterpret_cast<ushort4*>(dh)     = make_ushort4(hh[0],hh[1],hh[2],hh[3]);
        *reinterpret_cast<ushort4*>(dh + 4) = make_ushort4(hh[4],hh[5],hh[6],hh[7]);
        *reinterpret_cast<ushort4*>(dl)     = make_ushort4(ll[0],ll[1],ll[2],ll[3]);
        *reinterpret_cast<ushort4*>(dl + 4) = make_ushort4(ll[4],ll[5],ll[6],ll[7]);
    }
}

// ======================= Kernel A: QKV + attn + ln1 -> X2 to global =======================
__global__ __launch_bounds__(256, 3) void attn_mfma(
    const float* __restrict__ x,
    const float* __restrict__ bq, const float* __restrict__ bk, const float* __restrict__ bv,
    const float* __restrict__ g1, const float* __restrict__ be1,
    u16* __restrict__ wsp, int use_xt)
{
    extern __shared__ __align__(16) char pool[];
    float* ksum  = (float*)(pool + KSUM);
    float* zf    = (float*)(pool + ZDEN);
    float* stats = (float*)(pool + STATS);

    const int bi  = blockIdx.x;                    // 0..2047
    const int j_  = ((bi & 7) << 8) | (bi >> 3);   // XCD-chunked
    const int n0  = j_ * 2;
    const int b   = n0 >> 10;
    const int hw0 = n0 & 1023;
    const int tid = threadIdx.x;
    const int lane = tid & 63, wv = tid >> 6;
    const int l16  = lane & 15, quad = lane >> 4;

    // Preload Q weight panel (hidden under phase A)
    short8 wqh[6][2], wql[6][2];
    #pragma unroll
    for (int ks = 0; ks < 6; ++ks)
        #pragma unroll
        for (int nt = 0; nt < 2; ++nt) {
            const int n = (wv*2 + nt)*16 + l16;
            wqh[ks][nt] = *(const short8*)(wsp + WQH + n*KQK_ + ks*32 + quad*8);
            wql[ks][nt] = *(const short8*)(wsp + WQL + n*KQK_ + ks*32 + quad*8);
        }

    // Phase A: stage both tiles into AX
    if (use_xt) {
        #pragma unroll
        for (int tau = 0; tau < 2; ++tau) {
            const u16* xtb = wsp + XT + (size_t)(n0 + tau) * 8192;
            #pragma unroll
            for (int i = 0; i < 2; ++i) {
                int off = (tid + i*256) * 8;
                int t = off >> 7, c = off & 127;
                short8 vh = *reinterpret_cast<const short8*>(xtb + off);
                short8 vl = *reinterpret_cast<const short8*>(xtb + 4096 + off);
                *reinterpret_cast<short8*>(pool + AX_H + (tau*32 + t)*400 + c*2) = vh;
                *reinterpret_cast<short8*>(pool + AX_L + (tau*32 + t)*400 + c*2) = vl;
            }
        }
    } else {
        #pragma unroll
        for (int tau = 0; tau < 2; ++tau) {
            const float* xb = x + (size_t)b * (T_*C_*HW_) + hw0 + tau;
            #pragma unroll
            for (int i = 0; i < 16; ++i) {
                int idx = tid + i*256;
                float v = xb[(size_t)idx * HW_];
                int t = idx >> 7, c = idx & 127;
                u16 hb = f2b(v);
                *(u16*)(pool + AX_H + (tau*32 + t)*400 + c*2) = hb;
                *(u16*)(pool + AX_L + (tau*32 + t)*400 + c*2) = f2b(v - b2f(hb));
            }
        }
    }
    {   // guidance duplicated per tile rows
        const u16* gh = wsp + GSH + b*2048 + tid*8;
        const u16* gl = wsp + GSL + b*2048 + tid*8;
        int off = tid * 8;
        int t = off >> 6, jg = off & 63;
        short8 vh = *reinterpret_cast<const short8*>(gh);
        short8 vl = *reinterpret_cast<const short8*>(gl);
        *reinterpret_cast<short8*>(pool + AX_H + t*400 + 256 + jg*2) = vh;
        *reinterpret_cast<short8*>(pool + AX_L + t*400 + 256 + jg*2) = vl;
        *reinterpret_cast<short8*>(pool + AX_H + (32 + t)*400 + 256 + jg*2) = vh;
        *reinterpret_cast<short8*>(pool + AX_L + (32 + t)*400 + 256 + jg*2) = vl;
    }
    __syncthreads();

    short4v qfh[4][2], qfl[4][2];
    short4v kfh[4][2], kfl[4][2];
    short4v vfh[4][2], vfl[4][2];

    // Q (swapped)
    {
        f32x4 aq[4][2];
        #pragma unroll
        for (int mt = 0; mt < 4; ++mt)
            #pragma unroll
            for (int nt = 0; nt < 2; ++nt) aq[mt][nt] = (f32x4){0.f,0.f,0.f,0.f};
        #pragma unroll
        for (int ks = 0; ks < 6; ++ks) {
            short8 ah[4], al[4];
            #pragma unroll
            for (int mt = 0; mt < 4; ++mt) {
                ah[mt] = *(const short8*)(pool + AX_H + (mt*16 + l16)*400 + ks*64 + quad*16);
                al[mt] = *(const short8*)(pool + AX_L + (mt*16 + l16)*400 + ks*64 + quad*16);
            }
            #pragma unroll
            for (int nt = 0; nt < 2; ++nt)
                #pragma unroll
                for (int mt = 0; mt < 4; ++mt) { MFMA3(aq[mt][nt], wqh[ks][nt], wql[ks][nt], ah[mt], al[mt]); }
        }
        #pragma unroll
        for (int ct = 0; ct < 2; ++ct) {
            f32x4 bq4 = *(const f32x4*)(bq + wv*32 + ct*16 + quad*4);
            #pragma unroll
            for (int mt = 0; mt < 4; ++mt) {
                f32x4 qp;
                #pragma unroll
                for (int r = 0; r < 4; ++r) {
                    float q = aq[mt][ct][r] + bq4[r];
                    qp[r] = (q > 0.f) ? q + 1.f : __expf(q);
                }
                splitfrag(qp, qfh[mt][ct], qfl[mt][ct]);
            }
        }
    }

    // K + ksum
    {
        f32x4 ak[4][2];
        #pragma unroll
        for (int mt = 0; mt < 4; ++mt)
            #pragma unroll
            for (int nt = 0; nt < 2; ++nt) ak[mt][nt] = (f32x4){0.f,0.f,0.f,0.f};
        #pragma unroll
        for (int ks = 0; ks < 6; ++ks) {
            short8 ah[4], al[4];
            #pragma unroll
            for (int mt = 0; mt < 4; ++mt) {
                ah[mt] = *(const short8*)(pool + AX_H + (mt*16 + l16)*400 + ks*64 + quad*16);
                al[mt] = *(const short8*)(pool + AX_L + (mt*16 + l16)*400 + ks*64 + quad*16);
            }
            #pragma unroll
            for (int nt = 0; nt < 2; ++nt) {
                const int n = (wv*2 + nt)*16 + l16;
                short8 bh = *(const short8*)(wsp + WKH + n*KQK_ + ks*32 + quad*8);
                short8 bl = *(const short8*)(wsp + WKL + n*KQK_ + ks*32 + quad*8);
                #pragma unroll
                for (int mt = 0; mt < 4; ++mt) { MFMA3(ak[mt][nt], ah[mt], al[mt], bh, bl); }
            }
        }
        float sk[2][2] = {{0.f,0.f},{0.f,0.f}};
        #pragma unroll
        for (int nt = 0; nt < 2; ++nt) {
            float bias = bk[wv*32 + nt*16 + l16];
            #pragma unroll
            for (int mt = 0; mt < 4; ++mt) {
                f32x4 kp;
                #pragma unroll
                for (int r = 0; r < 4; ++r) {
                    float k = ak[mt][nt][r] + bias;
                    float v = (k > 0.f) ? k + 1.f : __expf(k);
                    kp[r] = v;
                    sk[mt >> 1][nt] += v;
                }
                splitfrag(kp, kfh[mt][nt], kfl[mt][nt]);
            }
        }
        #pragma unroll
        for (int tau = 0; tau < 2; ++tau)
            #pragma unroll
            for (int nt = 0; nt < 2; ++nt) {
                float s = sk[tau][nt];
                s += __shfl_xor(s, 16); s += __shfl_xor(s, 32);
                if (quad == 0) ksum[tau*128 + wv*32 + nt*16 + l16] = s;
            }
    }

    // V
    {
        f32x4 av[4][2];
        #pragma unroll
        for (int mt = 0; mt < 4; ++mt)
            #pragma unroll
            for (int nt = 0; nt < 2; ++nt) av[mt][nt] = (f32x4){0.f,0.f,0.f,0.f};
        #pragma unroll
        for (int ks = 0; ks < 4; ++ks) {
            short8 ah[4], al[4];
            #pragma unroll
            for (int mt = 0; mt < 4; ++mt) {
                ah[mt] = *(const short8*)(pool + AX_H + (mt*16 + l16)*400 + ks*64 + quad*16);
                al[mt] = *(const short8*)(pool + AX_L + (mt*16 + l16)*400 + ks*64 + quad*16);
            }
            #pragma unroll
            for (int nt = 0; nt < 2; ++nt) {
                const int n = (wv*2 + nt)*16 + l16;
                short8 bh = *(const short8*)(wsp + WVH + n*C_ + ks*32 + quad*8);
                short8 bl = *(const short8*)(wsp + WVL + n*C_ + ks*32 + quad*8);
                #pragma unroll
                for (int mt = 0; mt < 4; ++mt) { MFMA3(av[mt][nt], ah[mt], al[mt], bh, bl); }
            }
        }
        #pragma unroll
        for (int nt = 0; nt < 2; ++nt) {
            float bias = bv[wv*32 + nt*16 + l16];
            #pragma unroll
            for (int mt = 0; mt < 4; ++mt) {
                f32x4 vp;
                #pragma unroll
                for (int r = 0; r < 4; ++r) vp[r] = av[mt][nt][r] + bias;
                splitfrag(vp, vfh[mt][nt], vfl[mt][nt]);
            }
        }
    }

    // zden
    #pragma unroll
    for (int tau = 0; tau < 2; ++tau) {
        f32x4 ka0 = *(const f32x4*)(ksum + tau*128 + wv*32 + quad*4);
        f32x4 ka1 = *(const f32x4*)(ksum + tau*128 + wv*32 + 16 + quad*4);
        #pragma unroll
        for (int lt = 0; lt < 2; ++lt) {
            const int mt = tau*2 + lt;
            float p = 0.f;
            #pragma unroll
            for (int i = 0; i < 4; ++i) {
                p = fmaf(b2f((u16)(short)qfh[mt][0][i]) + b2f((u16)(short)qfl[mt][0][i]), ka0[i], p);
                p = fmaf(b2f((u16)(short)qfh[mt][1][i]) + b2f((u16)(short)qfl[mt][1][i]), ka1[i], p);
            }
            p += __shfl_xor(p, 16); p += __shfl_xor(p, 32);
            if (quad == 0) zf[tau*128 + wv*32 + lt*16 + l16] = 1.f / (p + 1e-6f);
        }
    }

    // KV
    short4v kvfh[2][2][2], kvfl[2][2][2];
    #pragma unroll
    for (int tau = 0; tau < 2; ++tau)
        #pragma unroll
        for (int dt = 0; dt < 2; ++dt)
            #pragma unroll
            for (int vt = 0; vt < 2; ++vt) {
                f32x4 kv = (f32x4){0.f,0.f,0.f,0.f};
                #pragma unroll
                for (int lt = 0; lt < 2; ++lt) {
                    const int mt = tau*2 + lt;
                    MFMA3_16(kv, kfh[mt][dt], kfl[mt][dt], vfh[mt][vt], vfl[mt][vt]);
                }
                splitfrag(kv, kvfh[tau][dt][vt], kvfl[tau][dt][vt]);
            }

    // ln1 stats
    {
        int t = tid >> 2, jj = tid & 3;
        const char* rp = pool + AX_H + t*400 + jj*64;
        float m = 0.f, s = 0.f;
        #pragma unroll
        for (int p8 = 0; p8 < 4; ++p8) {
            short8 h = *(const short8*)(rp + p8*16);
            short8 l = *(const short8*)(rp + (AX_L - AX_H) + p8*16);
            #pragma unroll
            for (int i = 0; i < 8; ++i) {
                float v = b2f((u16)h[i]) + b2f((u16)l[i]);
                m += v; s = fmaf(v, v, s);
            }
        }
        m += __shfl_xor(m, 1); s += __shfl_xor(s, 1);
        m += __shfl_xor(m, 2); s += __shfl_xor(s, 2);
        if (jj == 0) {
            float mu = m * (1.f/C_);
            stats[t]      = mu;
            stats[64 + t] = rsqrtf(s * (1.f/C_) - mu*mu + 1e-5f);
        }
    }
    __syncthreads();

    // Phase O: o1 = attn*z + ln1 residual
    f32x4 o1v[4][2];
    #pragma unroll
    for (int mt = 0; mt < 4; ++mt) {
        const int tau = mt >> 1;
        f32x4 zd4 = *(const f32x4*)(zf + tau*128 + wv*32 + (mt & 1)*16 + quad*4);
        f32x4 mu4 = *(const f32x4*)(stats + mt*16 + quad*4);
        f32x4 rs4 = *(const f32x4*)(stats + 64 + mt*16 + quad*4);
        #pragma unroll
        for (int vt = 0; vt < 2; ++vt) {
            f32x4 oa = (f32x4){0.f,0.f,0.f,0.f};
            #pragma unroll
            for (int dt = 0; dt < 2; ++dt) {
                MFMA3_16(oa, qfh[mt][dt], qfl[mt][dt], kvfh[tau][dt][vt], kvfl[tau][dt][vt]);
            }
            int ch = wv*32 + vt*16 + l16;
            float g1c = g1[ch], be1c = be1[ch];
            #pragma unroll
            for (int r = 0; r < 4; ++r) {
                int row = mt*16 + quad*4 + r;
                float xv = b2f(*(const u16*)(pool + AX_H + row*400 + ch*2))
                         + b2f(*(const u16*)(pool + AX_L + row*400 + ch*2));
                o1v[mt][vt][r] = oa[r]*zd4[r] + (xv - mu4[r])*rs4[r]*g1c + be1c;
            }
        }
    }
    __syncthreads();   // AX dead

    // X2 split planes into LDS overlay
    #pragma unroll
    for (int mt = 0; mt < 4; ++mt) {
        char* xb = pool + X2G(mt);
        #pragma unroll
        for (int vt = 0; vt < 2; ++vt) {
            int ch = wv*32 + vt*16 + l16;
            #pragma unroll
            for (int r = 0; r < 4; ++r) {
                u16 hb, lb; split2(o1v[mt][vt][r], hb, lb);
                int off = (quad*4 + r)*272 + ch*2;
                *(u16*)(xb + off)        = hb;
                *(u16*)(xb + 4352 + off) = lb;
            }
        }
    }
    __syncthreads();

    // Coalesced LDS -> global X2 (overwrites dead XT region)
    {
        u16* dst = wsp + XT + (size_t)n0 * 8192;
        #pragma unroll
        for (int i = 0; i < 8; ++i) {
            int cid = tid + i*256;              // 0..2047 short8 chunks
            int tau = cid >> 10;
            int rem = cid & 1023;
            int plane = rem >> 9;
            int rr = (rem >> 4) & 31;
            int c8 = (rem & 15) << 3;
            int grow = tau*32 + rr;
            const char* lsrc = pool + X2G(grow >> 4) + plane*4352 + (grow & 15)*272 + c8*2;
            short8 v = *reinterpret_cast<const short8*>(lsrc);
            *reinterpret_cast<short8*>(dst + (size_t)tau*8192 + plane*4096 + rr*128 + c8) = v;
        }
    }
}

// ======================= Kernel B: MLP (reads X2, writes y) =======================
__global__ __launch_bounds__(256, 4) void mlp_mfma(
    const float* __restrict__ b2, const u16* __restrict__ wsp,
    float* __restrict__ out)
{
    extern __shared__ __align__(16) char pool[];
    float* stats = (float*)(pool + BST);
    const float* acf = (const float*)wsp;

    const int bi = blockIdx.x;                  // 0..4095
    const int n  = ((bi & 7) << 9) | (bi >> 3); // XCD-chunked
    const int b  = n >> 10;
    const int hw = n & 1023;
    const int tid = threadIdx.x;
    const int lane = tid & 63, wv = tid >> 6;
    const int l16 = lane & 15, quad = lane >> 4;

    // Stage X2 tile from global (coalesced)
    {
        const u16* src = wsp + XT + (size_t)n * 8192;
        #pragma unroll
        for (int i = 0; i < 4; ++i) {
            int cid = tid + i*256;               // 0..1023
            int plane = cid >> 9;
            int rr = (cid >> 4) & 31;
            int c8 = (cid & 15) << 3;
            short8 v = *reinterpret_cast<const short8*>(src + plane*4096 + rr*128 + c8);
            *reinterpret_cast<short8*>(pool + BX2 + plane*8704 + rr*272 + c8*2) = v;
        }
    }
    __syncthreads();

    // ln2 stats from X2 (8 threads/row)
    {
        int row = tid >> 3, j = tid & 7;
        const char* rp = pool + BX2 + row*272 + j*32;
        short8 h0 = *(const short8*)(rp);
        short8 h1 = *(const short8*)(rp + 16);
        short8 l0 = *(const short8*)(rp + 8704);
        short8 l1 = *(const short8*)(rp + 8704 + 16);
        float m = 0.f, s = 0.f;
        #pragma unroll
        for (int i = 0; i < 8; ++i) {
            float v = b2f((u16)h0[i]) + b2f((u16)l0[i]);
            m += v; s = fmaf(v, v, s);
            v = b2f((u16)h1[i]) + b2f((u16)l1[i]);
            m += v; s = fmaf(v, v, s);
        }
        m += __shfl_xor(m, 1); s += __shfl_xor(s, 1);
        m += __shfl_xor(m, 2); s += __shfl_xor(s, 2);
        m += __shfl_xor(m, 4); s += __shfl_xor(s, 4);
        if (j == 0) {
            float mu = m * (1.f/C_);
            float rs = rsqrtf(s * (1.f/C_) - mu*mu + 1e-5f);
            stats[row]      = mu * rs;
            stats[32 + row] = rs;
        }
    }
    __syncthreads();

    // MLP: 4 chunks of 128 hm-channels
    f32x4 accO[2][2];
    #pragma unroll
    for (int mt = 0; mt < 2; ++mt)
        #pragma unroll
        for (int nt = 0; nt < 2; ++nt) accO[mt][nt] = (f32x4){0.f,0.f,0.f,0.f};

    #pragma unroll 1
    for (int mh = 0; mh < 4; ++mh) {
        {
            f32x4 accH[2][2];
            #pragma unroll
            for (int mt = 0; mt < 2; ++mt)
                #pragma unroll
                for (int nt = 0; nt < 2; ++nt) accH[mt][nt] = (f32x4){0.f,0.f,0.f,0.f};
            #pragma unroll
            for (int ks = 0; ks < 4; ++ks) {
                short8 ah[2], al[2];
                #pragma unroll
                for (int mt = 0; mt < 2; ++mt) {
                    const char* xb = pool + BX2 + (mt*16 + l16)*272 + ks*64 + quad*16;
                    ah[mt] = *(const short8*)(xb);
                    al[mt] = *(const short8*)(xb + 8704);
                }
                #pragma unroll
                for (int nt = 0; nt < 2; ++nt) {
                    const int gn = mh*128 + (wv*2 + nt)*16 + l16;
                    short8 bh = *(const short8*)(wsp + W1H + gn*C_ + ks*32 + quad*8);
                    short8 bl = *(const short8*)(wsp + W1L + gn*C_ + ks*32 + quad*8);
                    #pragma unroll
                    for (int mt = 0; mt < 2; ++mt) { MFMA3(accH[mt][nt], bh, bl, ah[mt], al[mt]); }
                }
            }
            // F epilogue: folded-ln2 + fast gelu -> HM
            #pragma unroll
            for (int nt = 0; nt < 2; ++nt) {
                int base = mh*128 + (wv*2 + nt)*16 + quad*4;
                f32x4 a4 = *(const f32x4*)(acf + ACF_A + base);
                f32x4 c4 = *(const f32x4*)(acf + ACF_C + base);
                int ch0 = (wv*2 + nt)*16 + quad*4;
                #pragma unroll
                for (int mt = 0; mt < 2; ++mt) {
                    int tk = mt*16 + l16;
                    float mrs = stats[tk], rsv = stats[32 + tk];
                    u16 hh[4], ll[4];
                    #pragma unroll
                    for (int r = 0; r < 4; ++r) {
                        float v = accH[mt][nt][r]*rsv - mrs*a4[r] + c4[r];
                        float ge = gelu_fast(v);
                        split2(ge, hh[r], ll[r]);
                    }
                    char* hb = pool + BHM + tk*272 + ch0*2;
                    *(u16x4*)(hb)        = (u16x4){hh[0],hh[1],hh[2],hh[3]};
                    *(u16x4*)(hb + 8704) = (u16x4){ll[0],ll[1],ll[2],ll[3]};
                }
            }
        }
        __syncthreads();
        {
            #pragma unroll
            for (int ks = 0; ks < 4; ++ks) {
                short8 ah[2], al[2];
                #pragma unroll
                for (int mt = 0; mt < 2; ++mt) {
                    const char* hb = pool + BHM + (mt*16 + l16)*272 + ks*64 + quad*16;
                    ah[mt] = *(const short8*)(hb);
                    al[mt] = *(const short8*)(hb + 8704);
                }
                #pragma unroll
                for (int nt = 0; nt < 2; ++nt) {
                    const int n2 = (wv*2 + nt)*16 + l16;
                    short8 bh = *(const short8*)(wsp + W2H + n2*C4_ + mh*128 + ks*32 + quad*8);
                    short8 bl = *(const short8*)(wsp + W2L + n2*C4_ + mh*128 + ks*32 + quad*8);
                    #pragma unroll
                    for (int mt = 0; mt < 2; ++mt) { MFMA3(accO[mt][nt], ah[mt], al[mt], bh, bl); }
                }
            }
        }
        if (mh < 3) __syncthreads();
    }

    // Epilogue: y = o1(X2 h+l) + mlp + b2, strided store
    {
        float* ob = out + (size_t)b * (T_*C_*HW_) + hw;
        #pragma unroll
        for (int mt = 0; mt < 2; ++mt) {
            #pragma unroll
            for (int nt = 0; nt < 2; ++nt) {
                int ch = wv*32 + nt*16 + l16;
                float b2c = b2[ch];
                #pragma unroll
                for (int r = 0; r < 4; ++r) {
                    int t = mt*16 + quad*4 + r;
                    float o1 = b2f(*(const u16*)(pool + BX2 + t*272 + ch*2))
                             + b2f(*(const u16*)(pool + BX2 + 8704 + t*272 + ch*2));
                    float y = o1 + accO[mt][nt][r] + b2c;
                    ob[(size_t)(t*C_ + ch) * HW_] = y;
                }
            }
        }
    }
}

extern "C" void kernel_launch(void* const* d_in, const int* in_sizes, int n_in,
                              void* d_out, int out_size, void* d_ws, size_t ws_size,
                              hipStream_t stream)
{
    const float* x   = (const float*)d_in[0];
    const float* gui = (const float*)d_in[1];
    const float* Wq  = (const float*)d_in[2];
    const float* bq  = (const float*)d_in[3];
    const float* Wk  = (const float*)d_in[4];
    const float* bk  = (const float*)d_in[5];
    const float* Wv  = (const float*)d_in[6];
    const float* bv  = (const float*)d_in[7];
    const float* g1  = (const float*)d_in[8];
    const float* be1 = (const float*)d_in[9];
    const float* g2  = (const float*)d_in[10];
    const float* be2 = (const float*)d_in[11];
    const float* W1  = (const float*)d_in[12];
    const float* b1  = (const float*)d_in[13];
    const float* W2  = (const float*)d_in[14];
    const float* b2  = (const float*)d_in[15];
    u16* wsp = (u16*)d_ws;

    int use_xt = (ws_size >= WS_NEED_BYTES) ? 1 : 0;

    prep_weights<<<dim3(802), dim3(256), 0, stream>>>(Wq, Wk, Wv, W1, W2, gui, g2, be2, b1, wsp);
    if (use_xt)
        transpose_x<<<dim3(8192), dim3(256), 0, stream>>>(x, wsp);

    (void)hipFuncSetAttribute((const void*)attn_mfma,
                              hipFuncAttributeMaxDynamicSharedMemorySize, POOLA);
    (void)hipFuncSetAttribute((const void*)mlp_mfma,
                              hipFuncAttributeMaxDynamicSharedMemorySize, POOLB);

    attn_mfma<<<dim3(2048), dim3(256), POOLA, stream>>>(
        x, bq, bk, bv, g1, be1, wsp, use_xt);
    mlp_mfma<<<dim3(4096), dim3(256), POOLB, stream>>>(
        b2, wsp, (float*)d_out);
}

// Round 11
// 430.130 us; speedup vs baseline: 1.3094x; 1.3094x over previous
//
#include <hip/hip_runtime.h>
#include <hip/hip_bf16.h>
#include <math.h>

#define T_   32
#define C_   128
#define GD_  64
#define KQK_ 192
#define NH_  4
#define HD_  32
#define C4_  512
#define HW_  1024

typedef unsigned short u16;
typedef __attribute__((ext_vector_type(8))) short short8;
typedef __attribute__((ext_vector_type(4))) short short4v;
typedef __attribute__((ext_vector_type(4))) float f32x4;
typedef __attribute__((ext_vector_type(4))) unsigned short u16x4;

// ---- ws layout ----
#define ACF_A 0
#define ACF_C 512
#define WQH 2048
#define WQL 26624
#define WKH 51200
#define WKL 75776
#define WVH 100352
#define WVL 116736
#define W1H 133120
#define W1L 198656
#define W2H 264192
#define W2L 329728
#define GSH 395264
#define GSL 403456
#define XT  411648           // [n][hi 4096 u16 | lo 4096 u16]; reused as X2 after attn
#define WS_NEED_BYTES (823296ull + 4096ull*8192ull*2ull)   // 67,932,160

// ---- Kernel A LDS (attn) ----
#define AX_H  0        // [64][200] u16 stride 400; rows 0-31 tile0, 32-63 tile1
#define AX_L  25600    // ends 51200
#define X2G(g) ((g)*8704)   // X2 overlay: group g of 16 rows, h row*272, l +4352; ends 34816
#define KSUM  51200    // 256 f32
#define ZDEN  52224    // 256 f32
#define STATS 53248    // 128 f32: mu1[64] rs1[64]
#define POOLA 53760    // x3 -> 3 blocks/CU

// ---- Kernel B LDS (mlp, M=64: two tiles) ----
// per tile 17408 B: h [32][136]u16 stride 272 (8704), l at +8704
#define BX2   0        // tiles at 0, 17408; ends 34816
#define BHM   34816    // tiles at 34816, 52224; ends 69632
#define BST   69632    // 128 f32: mu2*rs2[64], rs2[64]
#define POOLB 70144    // x2 = 140288 <= 163840 -> 2 blocks/CU

__device__ __forceinline__ float b2f(u16 u) {
    unsigned int x = ((unsigned int)u) << 16;
    float f; __builtin_memcpy(&f, &x, 4); return f;
}
__device__ __forceinline__ u16 f2b(float f) {
    __hip_bfloat16 h = __float2bfloat16(f);
    u16 u; __builtin_memcpy(&u, &h, 2); return u;
}
__device__ __forceinline__ void split2(float v, u16& h, u16& l) {
    h = f2b(v); l = f2b(v - b2f(h));
}
__device__ __forceinline__ void splitfrag(const f32x4 v, short4v& h, short4v& l) {
    u16 hh[4], ll[4];
    #pragma unroll
    for (int r = 0; r < 4; ++r) { hh[r] = f2b(v[r]); ll[r] = f2b(v[r] - b2f(hh[r])); }
    h = (short4v){(short)hh[0],(short)hh[1],(short)hh[2],(short)hh[3]};
    l = (short4v){(short)ll[0],(short)ll[1],(short)ll[2],(short)ll[3]};
}

// Branch-free gelu (A&S 7.1.26 erf, max err 1.5e-7)
__device__ __forceinline__ float gelu_fast(float v) {
    float a  = fabsf(v) * 0.70710678118654752f;
    float t  = __builtin_amdgcn_rcpf(fmaf(a, 0.3275911f, 1.f));
    float p  = t*(0.254829592f + t*(-0.284496736f + t*(1.421413741f
             + t*(-1.453152027f + t*1.061405429f))));
    float P  = p * __expf(-a*a);
    float hv = 0.5f * v;
    return (v > 0.f) ? v - hv*P : hv*P;
}

__device__ __forceinline__ f32x4 mfma16(short4v a, short4v b, f32x4 c) {
#if __has_builtin(__builtin_amdgcn_mfma_f32_16x16x16bf16_1k)
    return __builtin_amdgcn_mfma_f32_16x16x16bf16_1k(a, b, c, 0, 0, 0);
#else
    asm("v_mfma_f32_16x16x16_bf16 %0, %1, %2, %0" : "+v"(c) : "v"(a), "v"(b));
    return c;
#endif
}

#define MFMA3(acc, ah, al, bh, bl)                                          \
    acc = __builtin_amdgcn_mfma_f32_16x16x32_bf16(ah, bh, acc, 0, 0, 0);    \
    acc = __builtin_amdgcn_mfma_f32_16x16x32_bf16(ah, bl, acc, 0, 0, 0);    \
    acc = __builtin_amdgcn_mfma_f32_16x16x32_bf16(al, bh, acc, 0, 0, 0);

#define MFMA3_16(acc, ah, al, bh, bl)                                       \
    acc = mfma16(ah, bh, acc);                                              \
    acc = mfma16(ah, bl, acc);                                              \
    acc = mfma16(al, bh, acc);

// ---- prep: split weights + guidance + a/cpl ----
__global__ void prep_weights(const float* __restrict__ Wq, const float* __restrict__ Wk,
                             const float* __restrict__ Wv, const float* __restrict__ W1,
                             const float* __restrict__ W2, const float* __restrict__ gui,
                             const float* __restrict__ g2, const float* __restrict__ be2,
                             const float* __restrict__ b1,
                             u16* __restrict__ wsp)
{
    int e = blockIdx.x * 256 + threadIdx.x;
    if (e >= 204800) {
        int n = e - 204800;
        if (n >= 512) return;
        float a = 0.f, c = 0.f;
        for (int k = 0; k < 128; ++k) {
            float w = W1[k*512 + n];
            a = fmaf(w, g2[k], a);
            c = fmaf(w, be2[k], c);
        }
        float* acf = (float*)wsp;
        acf[ACF_A + n] = a;
        acf[ACF_C + n] = c + b1[n];
        return;
    }
    if (e >= 196608) {
        int idx = e - 196608;
        float v = gui[idx];
        u16 hb = f2b(v);
        wsp[GSH + idx] = hb;
        wsp[GSL + idx] = f2b(v - b2f(hb));
        return;
    }
    const float* src; int e2, k, n, K; int oh, ol; int isW1 = 0;
    if (e < 24576)       { src = Wq; e2 = e;          k = e2 >> 7; n = e2 & 127; K = KQK_; oh = WQH; ol = WQL; }
    else if (e < 49152)  { src = Wk; e2 = e - 24576;  k = e2 >> 7; n = e2 & 127; K = KQK_; oh = WKH; ol = WKL; }
    else if (e < 65536)  { src = Wv; e2 = e - 49152;  k = e2 >> 7; n = e2 & 127; K = C_;   oh = WVH; ol = WVL; }
    else if (e < 131072) { src = W1; e2 = e - 65536;  k = e2 >> 9; n = e2 & 511; K = C_;   oh = W1H; ol = W1L; isW1 = 1; }
    else                 { src = W2; e2 = e - 131072; k = e2 >> 7; n = e2 & 127; K = C4_;  oh = W2H; ol = W2L; }
    float w = src[e2];
    if (isW1) w *= g2[k];
    u16 hb = f2b(w);
    wsp[oh + n * K + k] = hb;
    wsp[ol + n * K + k] = f2b(w - b2f(hb));
}

// ---- transpose x (unchanged) ----
__global__ __launch_bounds__(256) void transpose_x(const float* __restrict__ x, u16* __restrict__ wsp)
{
    __shared__ float tile[32][65];
    int bid = blockIdx.x;
    int hq = bid & 15, cq = (bid >> 4) & 3, t = (bid >> 6) & 31, b = bid >> 11;
    int c0 = cq * 32, hw0 = hq * 64;
    int tid = threadIdx.x;
    {
        int i = tid >> 3, j8 = (tid & 7) * 8;
        const float* src = x + ((size_t)((b*32 + t)*128 + c0 + i))*1024 + hw0 + j8;
        float4 v0 = *reinterpret_cast<const float4*>(src);
        float4 v1 = *reinterpret_cast<const float4*>(src + 4);
        tile[i][j8+0]=v0.x; tile[i][j8+1]=v0.y; tile[i][j8+2]=v0.z; tile[i][j8+3]=v0.w;
        tile[i][j8+4]=v1.x; tile[i][j8+5]=v1.y; tile[i][j8+6]=v1.z; tile[i][j8+7]=v1.w;
    }
    __syncthreads();
    {
        int jj = tid >> 2, c8 = (tid & 3) * 8;
        int n = b*1024 + hw0 + jj;
        u16 hh[8], ll[8];
        #pragma unroll
        for (int ii = 0; ii < 8; ++ii) {
            float v = tile[c8 + ii][jj];
            u16 hb = f2b(v);
            hh[ii] = hb; ll[ii] = f2b(v - b2f(hb));
        }
        u16* dh = wsp + XT + (size_t)n*8192 + t*128 + c0 + c8;
        u16* dl = dh + 4096;
        *reinterpret_cast<ushort4*>(dh)     = make_ushort4(hh[0],hh[1],hh[2],hh[3]);
        *reinterpret_cast<ushort4*>(dh + 4) = make_ushort4(hh[4],hh[5],hh[6],hh[7]);
        *reinterpret_cast<ushort4*>(dl)     = make_ushort4(ll[0],ll[1],ll[2],ll[3]);
        *reinterpret_cast<ushort4*>(dl + 4) = make_ushort4(ll[4],ll[5],ll[6],ll[7]);
    }
}

// ======================= Kernel A: QKV + attn + ln1 -> X2 to global =======================
__global__ __launch_bounds__(256, 3) void attn_mfma(
    const float* __restrict__ x,
    const float* __restrict__ bq, const float* __restrict__ bk, const float* __restrict__ bv,
    const float* __restrict__ g1, const float* __restrict__ be1,
    u16* __restrict__ wsp, int use_xt)
{
    extern __shared__ __align__(16) char pool[];
    float* ksum  = (float*)(pool + KSUM);
    float* zf    = (float*)(pool + ZDEN);
    float* stats = (float*)(pool + STATS);

    const int bi  = blockIdx.x;                    // 0..2047
    const int j_  = ((bi & 7) << 8) | (bi >> 3);   // XCD-chunked
    const int n0  = j_ * 2;
    const int b   = n0 >> 10;
    const int hw0 = n0 & 1023;
    const int tid = threadIdx.x;
    const int lane = tid & 63, wv = tid >> 6;
    const int l16  = lane & 15, quad = lane >> 4;

    // Preload Q weight panel (hidden under phase A)
    short8 wqh[6][2], wql[6][2];
    #pragma unroll
    for (int ks = 0; ks < 6; ++ks)
        #pragma unroll
        for (int nt = 0; nt < 2; ++nt) {
            const int n = (wv*2 + nt)*16 + l16;
            wqh[ks][nt] = *(const short8*)(wsp + WQH + n*KQK_ + ks*32 + quad*8);
            wql[ks][nt] = *(const short8*)(wsp + WQL + n*KQK_ + ks*32 + quad*8);
        }

    // Phase A: stage both tiles into AX
    if (use_xt) {
        #pragma unroll
        for (int tau = 0; tau < 2; ++tau) {
            const u16* xtb = wsp + XT + (size_t)(n0 + tau) * 8192;
            #pragma unroll
            for (int i = 0; i < 2; ++i) {
                int off = (tid + i*256) * 8;
                int t = off >> 7, c = off & 127;
                short8 vh = *reinterpret_cast<const short8*>(xtb + off);
                short8 vl = *reinterpret_cast<const short8*>(xtb + 4096 + off);
                *reinterpret_cast<short8*>(pool + AX_H + (tau*32 + t)*400 + c*2) = vh;
                *reinterpret_cast<short8*>(pool + AX_L + (tau*32 + t)*400 + c*2) = vl;
            }
        }
    } else {
        #pragma unroll
        for (int tau = 0; tau < 2; ++tau) {
            const float* xb = x + (size_t)b * (T_*C_*HW_) + hw0 + tau;
            #pragma unroll
            for (int i = 0; i < 16; ++i) {
                int idx = tid + i*256;
                float v = xb[(size_t)idx * HW_];
                int t = idx >> 7, c = idx & 127;
                u16 hb = f2b(v);
                *(u16*)(pool + AX_H + (tau*32 + t)*400 + c*2) = hb;
                *(u16*)(pool + AX_L + (tau*32 + t)*400 + c*2) = f2b(v - b2f(hb));
            }
        }
    }
    {
        const u16* gh = wsp + GSH + b*2048 + tid*8;
        const u16* gl = wsp + GSL + b*2048 + tid*8;
        int off = tid * 8;
        int t = off >> 6, jg = off & 63;
        short8 vh = *reinterpret_cast<const short8*>(gh);
        short8 vl = *reinterpret_cast<const short8*>(gl);
        *reinterpret_cast<short8*>(pool + AX_H + t*400 + 256 + jg*2) = vh;
        *reinterpret_cast<short8*>(pool + AX_L + t*400 + 256 + jg*2) = vl;
        *reinterpret_cast<short8*>(pool + AX_H + (32 + t)*400 + 256 + jg*2) = vh;
        *reinterpret_cast<short8*>(pool + AX_L + (32 + t)*400 + 256 + jg*2) = vl;
    }
    __syncthreads();

    short4v qfh[4][2], qfl[4][2];
    short4v kfh[4][2], kfl[4][2];
    short4v vfh[4][2], vfl[4][2];

    // Q (swapped)
    {
        f32x4 aq[4][2];
        #pragma unroll
        for (int mt = 0; mt < 4; ++mt)
            #pragma unroll
            for (int nt = 0; nt < 2; ++nt) aq[mt][nt] = (f32x4){0.f,0.f,0.f,0.f};
        #pragma unroll
        for (int ks = 0; ks < 6; ++ks) {
            short8 ah[4], al[4];
            #pragma unroll
            for (int mt = 0; mt < 4; ++mt) {
                ah[mt] = *(const short8*)(pool + AX_H + (mt*16 + l16)*400 + ks*64 + quad*16);
                al[mt] = *(const short8*)(pool + AX_L + (mt*16 + l16)*400 + ks*64 + quad*16);
            }
            #pragma unroll
            for (int nt = 0; nt < 2; ++nt)
                #pragma unroll
                for (int mt = 0; mt < 4; ++mt) { MFMA3(aq[mt][nt], wqh[ks][nt], wql[ks][nt], ah[mt], al[mt]); }
        }
        #pragma unroll
        for (int ct = 0; ct < 2; ++ct) {
            f32x4 bq4 = *(const f32x4*)(bq + wv*32 + ct*16 + quad*4);
            #pragma unroll
            for (int mt = 0; mt < 4; ++mt) {
                f32x4 qp;
                #pragma unroll
                for (int r = 0; r < 4; ++r) {
                    float q = aq[mt][ct][r] + bq4[r];
                    qp[r] = (q > 0.f) ? q + 1.f : __expf(q);
                }
                splitfrag(qp, qfh[mt][ct], qfl[mt][ct]);
            }
        }
    }

    // K + ksum
    {
        f32x4 ak[4][2];
        #pragma unroll
        for (int mt = 0; mt < 4; ++mt)
            #pragma unroll
            for (int nt = 0; nt < 2; ++nt) ak[mt][nt] = (f32x4){0.f,0.f,0.f,0.f};
        #pragma unroll
        for (int ks = 0; ks < 6; ++ks) {
            short8 ah[4], al[4];
            #pragma unroll
            for (int mt = 0; mt < 4; ++mt) {
                ah[mt] = *(const short8*)(pool + AX_H + (mt*16 + l16)*400 + ks*64 + quad*16);
                al[mt] = *(const short8*)(pool + AX_L + (mt*16 + l16)*400 + ks*64 + quad*16);
            }
            #pragma unroll
            for (int nt = 0; nt < 2; ++nt) {
                const int n = (wv*2 + nt)*16 + l16;
                short8 bh = *(const short8*)(wsp + WKH + n*KQK_ + ks*32 + quad*8);
                short8 bl = *(const short8*)(wsp + WKL + n*KQK_ + ks*32 + quad*8);
                #pragma unroll
                for (int mt = 0; mt < 4; ++mt) { MFMA3(ak[mt][nt], ah[mt], al[mt], bh, bl); }
            }
        }
        float sk[2][2] = {{0.f,0.f},{0.f,0.f}};
        #pragma unroll
        for (int nt = 0; nt < 2; ++nt) {
            float bias = bk[wv*32 + nt*16 + l16];
            #pragma unroll
            for (int mt = 0; mt < 4; ++mt) {
                f32x4 kp;
                #pragma unroll
                for (int r = 0; r < 4; ++r) {
                    float k = ak[mt][nt][r] + bias;
                    float v = (k > 0.f) ? k + 1.f : __expf(k);
                    kp[r] = v;
                    sk[mt >> 1][nt] += v;
                }
                splitfrag(kp, kfh[mt][nt], kfl[mt][nt]);
            }
        }
        #pragma unroll
        for (int tau = 0; tau < 2; ++tau)
            #pragma unroll
            for (int nt = 0; nt < 2; ++nt) {
                float s = sk[tau][nt];
                s += __shfl_xor(s, 16); s += __shfl_xor(s, 32);
                if (quad == 0) ksum[tau*128 + wv*32 + nt*16 + l16] = s;
            }
    }

    // V
    {
        f32x4 av[4][2];
        #pragma unroll
        for (int mt = 0; mt < 4; ++mt)
            #pragma unroll
            for (int nt = 0; nt < 2; ++nt) av[mt][nt] = (f32x4){0.f,0.f,0.f,0.f};
        #pragma unroll
        for (int ks = 0; ks < 4; ++ks) {
            short8 ah[4], al[4];
            #pragma unroll
            for (int mt = 0; mt < 4; ++mt) {
                ah[mt] = *(const short8*)(pool + AX_H + (mt*16 + l16)*400 + ks*64 + quad*16);
                al[mt] = *(const short8*)(pool + AX_L + (mt*16 + l16)*400 + ks*64 + quad*16);
            }
            #pragma unroll
            for (int nt = 0; nt < 2; ++nt) {
                const int n = (wv*2 + nt)*16 + l16;
                short8 bh = *(const short8*)(wsp + WVH + n*C_ + ks*32 + quad*8);
                short8 bl = *(const short8*)(wsp + WVL + n*C_ + ks*32 + quad*8);
                #pragma unroll
                for (int mt = 0; mt < 4; ++mt) { MFMA3(av[mt][nt], ah[mt], al[mt], bh, bl); }
            }
        }
        #pragma unroll
        for (int nt = 0; nt < 2; ++nt) {
            float bias = bv[wv*32 + nt*16 + l16];
            #pragma unroll
            for (int mt = 0; mt < 4; ++mt) {
                f32x4 vp;
                #pragma unroll
                for (int r = 0; r < 4; ++r) vp[r] = av[mt][nt][r] + bias;
                splitfrag(vp, vfh[mt][nt], vfl[mt][nt]);
            }
        }
    }

    // zden
    #pragma unroll
    for (int tau = 0; tau < 2; ++tau) {
        f32x4 ka0 = *(const f32x4*)(ksum + tau*128 + wv*32 + quad*4);
        f32x4 ka1 = *(const f32x4*)(ksum + tau*128 + wv*32 + 16 + quad*4);
        #pragma unroll
        for (int lt = 0; lt < 2; ++lt) {
            const int mt = tau*2 + lt;
            float p = 0.f;
            #pragma unroll
            for (int i = 0; i < 4; ++i) {
                p = fmaf(b2f((u16)(short)qfh[mt][0][i]) + b2f((u16)(short)qfl[mt][0][i]), ka0[i], p);
                p = fmaf(b2f((u16)(short)qfh[mt][1][i]) + b2f((u16)(short)qfl[mt][1][i]), ka1[i], p);
            }
            p += __shfl_xor(p, 16); p += __shfl_xor(p, 32);
            if (quad == 0) zf[tau*128 + wv*32 + lt*16 + l16] = 1.f / (p + 1e-6f);
        }
    }

    // KV
    short4v kvfh[2][2][2], kvfl[2][2][2];
    #pragma unroll
    for (int tau = 0; tau < 2; ++tau)
        #pragma unroll
        for (int dt = 0; dt < 2; ++dt)
            #pragma unroll
            for (int vt = 0; vt < 2; ++vt) {
                f32x4 kv = (f32x4){0.f,0.f,0.f,0.f};
                #pragma unroll
                for (int lt = 0; lt < 2; ++lt) {
                    const int mt = tau*2 + lt;
                    MFMA3_16(kv, kfh[mt][dt], kfl[mt][dt], vfh[mt][vt], vfl[mt][vt]);
                }
                splitfrag(kv, kvfh[tau][dt][vt], kvfl[tau][dt][vt]);
            }

    // ln1 stats
    {
        int t = tid >> 2, jj = tid & 3;
        const char* rp = pool + AX_H + t*400 + jj*64;
        float m = 0.f, s = 0.f;
        #pragma unroll
        for (int p8 = 0; p8 < 4; ++p8) {
            short8 h = *(const short8*)(rp + p8*16);
            short8 l = *(const short8*)(rp + (AX_L - AX_H) + p8*16);
            #pragma unroll
            for (int i = 0; i < 8; ++i) {
                float v = b2f((u16)h[i]) + b2f((u16)l[i]);
                m += v; s = fmaf(v, v, s);
            }
        }
        m += __shfl_xor(m, 1); s += __shfl_xor(s, 1);
        m += __shfl_xor(m, 2); s += __shfl_xor(s, 2);
        if (jj == 0) {
            float mu = m * (1.f/C_);
            stats[t]      = mu;
            stats[64 + t] = rsqrtf(s * (1.f/C_) - mu*mu + 1e-5f);
        }
    }
    __syncthreads();

    // Phase O: o1 = attn*z + ln1 residual
    f32x4 o1v[4][2];
    #pragma unroll
    for (int mt = 0; mt < 4; ++mt) {
        const int tau = mt >> 1;
        f32x4 zd4 = *(const f32x4*)(zf + tau*128 + wv*32 + (mt & 1)*16 + quad*4);
        f32x4 mu4 = *(const f32x4*)(stats + mt*16 + quad*4);
        f32x4 rs4 = *(const f32x4*)(stats + 64 + mt*16 + quad*4);
        #pragma unroll
        for (int vt = 0; vt < 2; ++vt) {
            f32x4 oa = (f32x4){0.f,0.f,0.f,0.f};
            #pragma unroll
            for (int dt = 0; dt < 2; ++dt) {
                MFMA3_16(oa, qfh[mt][dt], qfl[mt][dt], kvfh[tau][dt][vt], kvfl[tau][dt][vt]);
            }
            int ch = wv*32 + vt*16 + l16;
            float g1c = g1[ch], be1c = be1[ch];
            #pragma unroll
            for (int r = 0; r < 4; ++r) {
                int row = mt*16 + quad*4 + r;
                float xv = b2f(*(const u16*)(pool + AX_H + row*400 + ch*2))
                         + b2f(*(const u16*)(pool + AX_L + row*400 + ch*2));
                o1v[mt][vt][r] = oa[r]*zd4[r] + (xv - mu4[r])*rs4[r]*g1c + be1c;
            }
        }
    }
    __syncthreads();   // AX dead

    // X2 split planes into LDS overlay
    #pragma unroll
    for (int mt = 0; mt < 4; ++mt) {
        char* xb = pool + X2G(mt);
        #pragma unroll
        for (int vt = 0; vt < 2; ++vt) {
            int ch = wv*32 + vt*16 + l16;
            #pragma unroll
            for (int r = 0; r < 4; ++r) {
                u16 hb, lb; split2(o1v[mt][vt][r], hb, lb);
                int off = (quad*4 + r)*272 + ch*2;
                *(u16*)(xb + off)        = hb;
                *(u16*)(xb + 4352 + off) = lb;
            }
        }
    }
    __syncthreads();

    // Coalesced LDS -> global X2 (overwrites dead XT region)
    {
        u16* dst = wsp + XT + (size_t)n0 * 8192;
        #pragma unroll
        for (int i = 0; i < 8; ++i) {
            int cid = tid + i*256;              // 0..2047 short8 chunks
            int tau = cid >> 10;
            int rem = cid & 1023;
            int plane = rem >> 9;
            int rr = (rem >> 4) & 31;
            int c8 = (rem & 15) << 3;
            int grow = tau*32 + rr;
            const char* lsrc = pool + X2G(grow >> 4) + plane*4352 + (grow & 15)*272 + c8*2;
            short8 v = *reinterpret_cast<const short8*>(lsrc);
            *reinterpret_cast<short8*>(dst + (size_t)tau*8192 + plane*4096 + rr*128 + c8) = v;
        }
    }
}

// ======================= Kernel B: MLP M=64, W1/W2 panels in registers =======================
__global__ __launch_bounds__(256, 2) void mlp_mfma(
    const float* __restrict__ b2, const u16* __restrict__ wsp,
    float* __restrict__ out)
{
    extern __shared__ __align__(16) char pool[];
    float* stats = (float*)(pool + BST);
    const float* acf = (const float*)wsp;

    const int bi = blockIdx.x;                  // 0..2047
    const int j_ = ((bi & 7) << 8) | (bi >> 3); // XCD-chunked
    const int n0 = j_ * 2;                      // tiles n0, n0+1
    const int b  = n0 >> 10;
    const int hw0 = n0 & 1023;
    const int tid = threadIdx.x;
    const int lane = tid & 63, wv = tid >> 6;
    const int l16 = lane & 15, quad = lane >> 4;

    // Preload W1 panel for mh=0 (hidden under X2 staging)
    short8 w1h[4][2], w1l[4][2], w2h[4][2], w2l[4][2];
    #pragma unroll
    for (int ks = 0; ks < 4; ++ks)
        #pragma unroll
        for (int nt = 0; nt < 2; ++nt) {
            const int gn = (wv*2 + nt)*16 + l16;
            w1h[ks][nt] = *(const short8*)(wsp + W1H + gn*C_ + ks*32 + quad*8);
            w1l[ks][nt] = *(const short8*)(wsp + W1L + gn*C_ + ks*32 + quad*8);
        }

    // Stage both X2 tiles from global (coalesced)
    {
        const u16* src = wsp + XT + (size_t)n0 * 8192;
        #pragma unroll
        for (int i = 0; i < 8; ++i) {
            int cid = tid + i*256;               // 0..2047
            int tau = cid >> 10;
            int rem = cid & 1023;
            int plane = rem >> 9;
            int rr = (rem >> 4) & 31;
            int c8 = (rem & 15) << 3;
            short8 v = *reinterpret_cast<const short8*>(src + (size_t)tau*8192 + plane*4096 + rr*128 + c8);
            *reinterpret_cast<short8*>(pool + BX2 + tau*17408 + plane*8704 + rr*272 + c8*2) = v;
        }
    }
    __syncthreads();

    // ln2 stats (4 threads/row, 64 rows)
    {
        int t = tid >> 2, jj = tid & 3;
        int tau = t >> 5, rr = t & 31;
        const char* rp = pool + BX2 + tau*17408 + rr*272 + jj*64;
        float m = 0.f, s = 0.f;
        #pragma unroll
        for (int p8 = 0; p8 < 4; ++p8) {
            short8 h = *(const short8*)(rp + p8*16);
            short8 l = *(const short8*)(rp + 8704 + p8*16);
            #pragma unroll
            for (int i = 0; i < 8; ++i) {
                float v = b2f((u16)h[i]) + b2f((u16)l[i]);
                m += v; s = fmaf(v, v, s);
            }
        }
        m += __shfl_xor(m, 1); s += __shfl_xor(s, 1);
        m += __shfl_xor(m, 2); s += __shfl_xor(s, 2);
        if (jj == 0) {
            float mu = m * (1.f/C_);
            float rs = rsqrtf(s * (1.f/C_) - mu*mu + 1e-5f);
            stats[t]      = mu * rs;
            stats[64 + t] = rs;
        }
    }
    __syncthreads();

    // MLP: 4 chunks of 128 hm-channels, M=64
    f32x4 accO[4][2];   // [mt][nt]: row = mt*16+quad*4+r, out_ch = (wv*2+nt)*16+l16
    #pragma unroll
    for (int mt = 0; mt < 4; ++mt)
        #pragma unroll
        for (int nt = 0; nt < 2; ++nt) accO[mt][nt] = (f32x4){0.f,0.f,0.f,0.f};

    #pragma unroll 1
    for (int mh = 0; mh < 4; ++mh) {
        {
            f32x4 accH[4][2];
            #pragma unroll
            for (int mt = 0; mt < 4; ++mt)
                #pragma unroll
                for (int nt = 0; nt < 2; ++nt) accH[mt][nt] = (f32x4){0.f,0.f,0.f,0.f};
            #pragma unroll
            for (int ks = 0; ks < 4; ++ks) {
                short8 ah[4], al[4];
                #pragma unroll
                for (int mt = 0; mt < 4; ++mt) {
                    const char* xb = pool + BX2 + (mt >> 1)*17408 + ((mt & 1)*16 + l16)*272 + ks*64 + quad*16;
                    ah[mt] = *(const short8*)(xb);
                    al[mt] = *(const short8*)(xb + 8704);
                }
                #pragma unroll
                for (int nt = 0; nt < 2; ++nt)
                    #pragma unroll
                    for (int mt = 0; mt < 4; ++mt) { MFMA3(accH[mt][nt], w1h[ks][nt], w1l[ks][nt], ah[mt], al[mt]); }
            }
            // issue W2 panel for this chunk (hides under F epilogue)
            #pragma unroll
            for (int ks = 0; ks < 4; ++ks)
                #pragma unroll
                for (int nt = 0; nt < 2; ++nt) {
                    const int n2 = (wv*2 + nt)*16 + l16;
                    w2h[ks][nt] = *(const short8*)(wsp + W2H + n2*C4_ + mh*128 + ks*32 + quad*8);
                    w2l[ks][nt] = *(const short8*)(wsp + W2L + n2*C4_ + mh*128 + ks*32 + quad*8);
                }
            // F epilogue: folded-ln2 + fast gelu -> HM
            #pragma unroll
            for (int nt = 0; nt < 2; ++nt) {
                int base = mh*128 + (wv*2 + nt)*16 + quad*4;
                f32x4 a4 = *(const f32x4*)(acf + ACF_A + base);
                f32x4 c4 = *(const f32x4*)(acf + ACF_C + base);
                int ch0 = (wv*2 + nt)*16 + quad*4;
                #pragma unroll
                for (int mt = 0; mt < 4; ++mt) {
                    int tkg = mt*16 + l16;
                    float mrs = stats[tkg], rsv = stats[64 + tkg];
                    u16 hh[4], ll[4];
                    #pragma unroll
                    for (int r = 0; r < 4; ++r) {
                        float v = accH[mt][nt][r]*rsv - mrs*a4[r] + c4[r];
                        float ge = gelu_fast(v);
                        split2(ge, hh[r], ll[r]);
                    }
                    char* hb = pool + BHM + (mt >> 1)*17408 + ((mt & 1)*16 + l16)*272 + ch0*2;
                    *(u16x4*)(hb)        = (u16x4){hh[0],hh[1],hh[2],hh[3]};
                    *(u16x4*)(hb + 8704) = (u16x4){ll[0],ll[1],ll[2],ll[3]};
                }
            }
        }
        __syncthreads();
        {
            #pragma unroll
            for (int ks = 0; ks < 4; ++ks) {
                short8 ah[4], al[4];
                #pragma unroll
                for (int mt = 0; mt < 4; ++mt) {
                    const char* hb = pool + BHM + (mt >> 1)*17408 + ((mt & 1)*16 + l16)*272 + ks*64 + quad*16;
                    ah[mt] = *(const short8*)(hb);
                    al[mt] = *(const short8*)(hb + 8704);
                }
                #pragma unroll
                for (int nt = 0; nt < 2; ++nt)
                    #pragma unroll
                    for (int mt = 0; mt < 4; ++mt) { MFMA3(accO[mt][nt], ah[mt], al[mt], w2h[ks][nt], w2l[ks][nt]); }
            }
            // issue W1 panel for next chunk (hides under G + barrier)
            if (mh < 3) {
                #pragma unroll
                for (int ks = 0; ks < 4; ++ks)
                    #pragma unroll
                    for (int nt = 0; nt < 2; ++nt) {
                        const int gn = (mh+1)*128 + (wv*2 + nt)*16 + l16;
                        w1h[ks][nt] = *(const short8*)(wsp + W1H + gn*C_ + ks*32 + quad*8);
                        w1l[ks][nt] = *(const short8*)(wsp + W1L + gn*C_ + ks*32 + quad*8);
                    }
            }
        }
        if (mh < 3) __syncthreads();
    }

    // Epilogue: y = o1(X2 h+l) + mlp + b2, strided store (two tiles)
    {
        float* obase = out + (size_t)b * (T_*C_*HW_) + hw0;
        #pragma unroll
        for (int mt = 0; mt < 4; ++mt) {
            const int tau = mt >> 1;
            float* ob = obase + tau;
            #pragma unroll
            for (int nt = 0; nt < 2; ++nt) {
                int ch = wv*32 + nt*16 + l16;
                float b2c = b2[ch];
                #pragma unroll
                for (int r = 0; r < 4; ++r) {
                    int t = (mt & 1)*16 + quad*4 + r;
                    const char* xp = pool + BX2 + tau*17408 + t*272 + ch*2;
                    float o1 = b2f(*(const u16*)(xp)) + b2f(*(const u16*)(xp + 8704));
                    float y = o1 + accO[mt][nt][r] + b2c;
                    ob[(size_t)(t*C_ + ch) * HW_] = y;
                }
            }
        }
    }
}

extern "C" void kernel_launch(void* const* d_in, const int* in_sizes, int n_in,
                              void* d_out, int out_size, void* d_ws, size_t ws_size,
                              hipStream_t stream)
{
    const float* x   = (const float*)d_in[0];
    const float* gui = (const float*)d_in[1];
    const float* Wq  = (const float*)d_in[2];
    const float* bq  = (const float*)d_in[3];
    const float* Wk  = (const float*)d_in[4];
    const float* bk  = (const float*)d_in[5];
    const float* Wv  = (const float*)d_in[6];
    const float* bv  = (const float*)d_in[7];
    const float* g1  = (const float*)d_in[8];
    const float* be1 = (const float*)d_in[9];
    const float* g2  = (const float*)d_in[10];
    const float* be2 = (const float*)d_in[11];
    const float* W1  = (const float*)d_in[12];
    const float* b1  = (const float*)d_in[13];
    const float* W2  = (const float*)d_in[14];
    const float* b2  = (const float*)d_in[15];
    u16* wsp = (u16*)d_ws;

    int use_xt = (ws_size >= WS_NEED_BYTES) ? 1 : 0;

    prep_weights<<<dim3(802), dim3(256), 0, stream>>>(Wq, Wk, Wv, W1, W2, gui, g2, be2, b1, wsp);
    if (use_xt)
        transpose_x<<<dim3(8192), dim3(256), 0, stream>>>(x, wsp);

    (void)hipFuncSetAttribute((const void*)attn_mfma,
                              hipFuncAttributeMaxDynamicSharedMemorySize, POOLA);
    (void)hipFuncSetAttribute((const void*)mlp_mfma,
                              hipFuncAttributeMaxDynamicSharedMemorySize, POOLB);

    attn_mfma<<<dim3(2048), dim3(256), POOLA, stream>>>(
        x, bq, bk, bv, g1, be1, wsp, use_xt);
    mlp_mfma<<<dim3(2048), dim3(256), POOLB, stream>>>(
        b2, wsp, (float*)d_out);
}

// Round 12
// 420.977 us; speedup vs baseline: 1.3379x; 1.0217x over previous
//
#include <hip/hip_runtime.h>
#include <hip/hip_bf16.h>
#include <math.h>

#define T_   32
#define C_   128
#define GD_  64
#define KQK_ 192
#define NH_  4
#define HD_  32
#define C4_  512
#define HW_  1024

typedef unsigned short u16;
typedef __attribute__((ext_vector_type(8))) short short8;
typedef __attribute__((ext_vector_type(4))) short short4v;
typedef __attribute__((ext_vector_type(4))) float f32x4;
typedef __attribute__((ext_vector_type(4))) unsigned short u16x4;

// ---- ws layout ----
#define ACF_A 0
#define ACF_C 512
#define WQH 2048
#define WQL 26624
#define WKH 51200
#define WKL 75776
#define WVH 100352
#define WVL 116736
#define W1H 133120
#define W1L 198656
#define W2H 264192
#define W2L 329728
#define GSH 395264
#define GSL 403456
#define XT  411648           // [n][hi 4096 u16 | lo 4096 u16]; reused as X2 after attn
#define WS_NEED_BYTES (823296ull + 4096ull*8192ull*2ull)   // 67,932,160

// ---- Kernel A LDS (attn) ----
#define AX_H  0        // [64][200] u16 stride 400; rows 0-31 tile0, 32-63 tile1
#define AX_L  25600    // ends 51200
#define X2G(g) ((g)*8704)   // X2 overlay: group g of 16 rows, h row*272, l +4352; ends 34816
#define KSUM  51200    // 256 f32
#define ZDEN  52224    // 256 f32
#define STATS 53248    // 128 f32: mu1[64] rs1[64]
#define POOLA 53760

// ---- Kernel B LDS (mlp, M=64: two tiles) ----
// per tile 17408 B: h [32][136]u16 stride 272 (8704), l at +8704
#define BX2   0        // tiles at 0, 17408; ends 34816
#define BHM   34816    // tiles at 34816, 52224; ends 69632
#define BST   69632    // 128 f32: mu2*rs2[64], rs2[64]
#define POOLB 70144    // x2 = 140288 <= 163840 -> 2 blocks/CU

__device__ __forceinline__ float b2f(u16 u) {
    unsigned int x = ((unsigned int)u) << 16;
    float f; __builtin_memcpy(&f, &x, 4); return f;
}
__device__ __forceinline__ u16 f2b(float f) {
    __hip_bfloat16 h = __float2bfloat16(f);
    u16 u; __builtin_memcpy(&u, &h, 2); return u;
}
__device__ __forceinline__ void split2(float v, u16& h, u16& l) {
    h = f2b(v); l = f2b(v - b2f(h));
}
__device__ __forceinline__ void splitfrag(const f32x4 v, short4v& h, short4v& l) {
    u16 hh[4], ll[4];
    #pragma unroll
    for (int r = 0; r < 4; ++r) { hh[r] = f2b(v[r]); ll[r] = f2b(v[r] - b2f(hh[r])); }
    h = (short4v){(short)hh[0],(short)hh[1],(short)hh[2],(short)hh[3]};
    l = (short4v){(short)ll[0],(short)ll[1],(short)ll[2],(short)ll[3]};
}

// Branch-free gelu (A&S 7.1.26 erf, max err 1.5e-7)
__device__ __forceinline__ float gelu_fast(float v) {
    float a  = fabsf(v) * 0.70710678118654752f;
    float t  = __builtin_amdgcn_rcpf(fmaf(a, 0.3275911f, 1.f));
    float p  = t*(0.254829592f + t*(-0.284496736f + t*(1.421413741f
             + t*(-1.453152027f + t*1.061405429f))));
    float P  = p * __expf(-a*a);
    float hv = 0.5f * v;
    return (v > 0.f) ? v - hv*P : hv*P;
}

__device__ __forceinline__ f32x4 mfma16(short4v a, short4v b, f32x4 c) {
#if __has_builtin(__builtin_amdgcn_mfma_f32_16x16x16bf16_1k)
    return __builtin_amdgcn_mfma_f32_16x16x16bf16_1k(a, b, c, 0, 0, 0);
#else
    asm("v_mfma_f32_16x16x16_bf16 %0, %1, %2, %0" : "+v"(c) : "v"(a), "v"(b));
    return c;
#endif
}

#define MFMA3(acc, ah, al, bh, bl)                                          \
    acc = __builtin_amdgcn_mfma_f32_16x16x32_bf16(ah, bh, acc, 0, 0, 0);    \
    acc = __builtin_amdgcn_mfma_f32_16x16x32_bf16(ah, bl, acc, 0, 0, 0);    \
    acc = __builtin_amdgcn_mfma_f32_16x16x32_bf16(al, bh, acc, 0, 0, 0);

#define MFMA3_16(acc, ah, al, bh, bl)                                       \
    acc = mfma16(ah, bh, acc);                                              \
    acc = mfma16(ah, bl, acc);                                              \
    acc = mfma16(al, bh, acc);

// ---- prep: split weights + guidance + a/cpl ----
__global__ void prep_weights(const float* __restrict__ Wq, const float* __restrict__ Wk,
                             const float* __restrict__ Wv, const float* __restrict__ W1,
                             const float* __restrict__ W2, const float* __restrict__ gui,
                             const float* __restrict__ g2, const float* __restrict__ be2,
                             const float* __restrict__ b1,
                             u16* __restrict__ wsp)
{
    int e = blockIdx.x * 256 + threadIdx.x;
    if (e >= 204800) {
        int n = e - 204800;
        if (n >= 512) return;
        float a = 0.f, c = 0.f;
        for (int k = 0; k < 128; ++k) {
            float w = W1[k*512 + n];
            a = fmaf(w, g2[k], a);
            c = fmaf(w, be2[k], c);
        }
        float* acf = (float*)wsp;
        acf[ACF_A + n] = a;
        acf[ACF_C + n] = c + b1[n];
        return;
    }
    if (e >= 196608) {
        int idx = e - 196608;
        float v = gui[idx];
        u16 hb = f2b(v);
        wsp[GSH + idx] = hb;
        wsp[GSL + idx] = f2b(v - b2f(hb));
        return;
    }
    const float* src; int e2, k, n, K; int oh, ol; int isW1 = 0;
    if (e < 24576)       { src = Wq; e2 = e;          k = e2 >> 7; n = e2 & 127; K = KQK_; oh = WQH; ol = WQL; }
    else if (e < 49152)  { src = Wk; e2 = e - 24576;  k = e2 >> 7; n = e2 & 127; K = KQK_; oh = WKH; ol = WKL; }
    else if (e < 65536)  { src = Wv; e2 = e - 49152;  k = e2 >> 7; n = e2 & 127; K = C_;   oh = WVH; ol = WVL; }
    else if (e < 131072) { src = W1; e2 = e - 65536;  k = e2 >> 9; n = e2 & 511; K = C_;   oh = W1H; ol = W1L; isW1 = 1; }
    else                 { src = W2; e2 = e - 131072; k = e2 >> 7; n = e2 & 127; K = C4_;  oh = W2H; ol = W2L; }
    float w = src[e2];
    if (isW1) w *= g2[k];
    u16 hb = f2b(w);
    wsp[oh + n * K + k] = hb;
    wsp[ol + n * K + k] = f2b(w - b2f(hb));
}

// ---- transpose x (unchanged) ----
__global__ __launch_bounds__(256) void transpose_x(const float* __restrict__ x, u16* __restrict__ wsp)
{
    __shared__ float tile[32][65];
    int bid = blockIdx.x;
    int hq = bid & 15, cq = (bid >> 4) & 3, t = (bid >> 6) & 31, b = bid >> 11;
    int c0 = cq * 32, hw0 = hq * 64;
    int tid = threadIdx.x;
    {
        int i = tid >> 3, j8 = (tid & 7) * 8;
        const float* src = x + ((size_t)((b*32 + t)*128 + c0 + i))*1024 + hw0 + j8;
        float4 v0 = *reinterpret_cast<const float4*>(src);
        float4 v1 = *reinterpret_cast<const float4*>(src + 4);
        tile[i][j8+0]=v0.x; tile[i][j8+1]=v0.y; tile[i][j8+2]=v0.z; tile[i][j8+3]=v0.w;
        tile[i][j8+4]=v1.x; tile[i][j8+5]=v1.y; tile[i][j8+6]=v1.z; tile[i][j8+7]=v1.w;
    }
    __syncthreads();
    {
        int jj = tid >> 2, c8 = (tid & 3) * 8;
        int n = b*1024 + hw0 + jj;
        u16 hh[8], ll[8];
        #pragma unroll
        for (int ii = 0; ii < 8; ++ii) {
            float v = tile[c8 + ii][jj];
            u16 hb = f2b(v);
            hh[ii] = hb; ll[ii] = f2b(v - b2f(hb));
        }
        u16* dh = wsp + XT + (size_t)n*8192 + t*128 + c0 + c8;
        u16* dl = dh + 4096;
        *reinterpret_cast<ushort4*>(dh)     = make_ushort4(hh[0],hh[1],hh[2],hh[3]);
        *reinterpret_cast<ushort4*>(dh + 4) = make_ushort4(hh[4],hh[5],hh[6],hh[7]);
        *reinterpret_cast<ushort4*>(dl)     = make_ushort4(ll[0],ll[1],ll[2],ll[3]);
        *reinterpret_cast<ushort4*>(dl + 4) = make_ushort4(ll[4],ll[5],ll[6],ll[7]);
    }
}

// ======================= Kernel A: QKV + attn + ln1 -> X2 to global =======================
__global__ __launch_bounds__(256, 2) void attn_mfma(
    const float* __restrict__ x,
    const float* __restrict__ bq, const float* __restrict__ bk, const float* __restrict__ bv,
    const float* __restrict__ g1, const float* __restrict__ be1,
    u16* __restrict__ wsp, int use_xt)
{
    extern __shared__ __align__(16) char pool[];
    float* ksum  = (float*)(pool + KSUM);
    float* zf    = (float*)(pool + ZDEN);
    float* stats = (float*)(pool + STATS);

    const int bi  = blockIdx.x;                    // 0..2047
    const int j_  = ((bi & 7) << 8) | (bi >> 3);   // XCD-chunked
    const int n0  = j_ * 2;
    const int b   = n0 >> 10;
    const int hw0 = n0 & 1023;
    const int tid = threadIdx.x;
    const int lane = tid & 63, wv = tid >> 6;
    const int l16  = lane & 15, quad = lane >> 4;

    // Preload Q weight panel (hidden under phase A)
    short8 wqh[6][2], wql[6][2];
    #pragma unroll
    for (int ks = 0; ks < 6; ++ks)
        #pragma unroll
        for (int nt = 0; nt < 2; ++nt) {
            const int n = (wv*2 + nt)*16 + l16;
            wqh[ks][nt] = *(const short8*)(wsp + WQH + n*KQK_ + ks*32 + quad*8);
            wql[ks][nt] = *(const short8*)(wsp + WQL + n*KQK_ + ks*32 + quad*8);
        }

    // Phase A: stage both tiles into AX
    if (use_xt) {
        #pragma unroll
        for (int tau = 0; tau < 2; ++tau) {
            const u16* xtb = wsp + XT + (size_t)(n0 + tau) * 8192;
            #pragma unroll
            for (int i = 0; i < 2; ++i) {
                int off = (tid + i*256) * 8;
                int t = off >> 7, c = off & 127;
                short8 vh = *reinterpret_cast<const short8*>(xtb + off);
                short8 vl = *reinterpret_cast<const short8*>(xtb + 4096 + off);
                *reinterpret_cast<short8*>(pool + AX_H + (tau*32 + t)*400 + c*2) = vh;
                *reinterpret_cast<short8*>(pool + AX_L + (tau*32 + t)*400 + c*2) = vl;
            }
        }
    } else {
        #pragma unroll
        for (int tau = 0; tau < 2; ++tau) {
            const float* xb = x + (size_t)b * (T_*C_*HW_) + hw0 + tau;
            #pragma unroll
            for (int i = 0; i < 16; ++i) {
                int idx = tid + i*256;
                float v = xb[(size_t)idx * HW_];
                int t = idx >> 7, c = idx & 127;
                u16 hb = f2b(v);
                *(u16*)(pool + AX_H + (tau*32 + t)*400 + c*2) = hb;
                *(u16*)(pool + AX_L + (tau*32 + t)*400 + c*2) = f2b(v - b2f(hb));
            }
        }
    }
    {
        const u16* gh = wsp + GSH + b*2048 + tid*8;
        const u16* gl = wsp + GSL + b*2048 + tid*8;
        int off = tid * 8;
        int t = off >> 6, jg = off & 63;
        short8 vh = *reinterpret_cast<const short8*>(gh);
        short8 vl = *reinterpret_cast<const short8*>(gl);
        *reinterpret_cast<short8*>(pool + AX_H + t*400 + 256 + jg*2) = vh;
        *reinterpret_cast<short8*>(pool + AX_L + t*400 + 256 + jg*2) = vl;
        *reinterpret_cast<short8*>(pool + AX_H + (32 + t)*400 + 256 + jg*2) = vh;
        *reinterpret_cast<short8*>(pool + AX_L + (32 + t)*400 + 256 + jg*2) = vl;
    }
    __syncthreads();

    short4v qfh[4][2], qfl[4][2];
    short4v kfh[4][2], kfl[4][2];
    short4v vfh[4][2], vfl[4][2];

    // Q (swapped)
    {
        f32x4 aq[4][2];
        #pragma unroll
        for (int mt = 0; mt < 4; ++mt)
            #pragma unroll
            for (int nt = 0; nt < 2; ++nt) aq[mt][nt] = (f32x4){0.f,0.f,0.f,0.f};
        #pragma unroll
        for (int ks = 0; ks < 6; ++ks) {
            short8 ah[4], al[4];
            #pragma unroll
            for (int mt = 0; mt < 4; ++mt) {
                ah[mt] = *(const short8*)(pool + AX_H + (mt*16 + l16)*400 + ks*64 + quad*16);
                al[mt] = *(const short8*)(pool + AX_L + (mt*16 + l16)*400 + ks*64 + quad*16);
            }
            #pragma unroll
            for (int nt = 0; nt < 2; ++nt)
                #pragma unroll
                for (int mt = 0; mt < 4; ++mt) { MFMA3(aq[mt][nt], wqh[ks][nt], wql[ks][nt], ah[mt], al[mt]); }
        }
        #pragma unroll
        for (int ct = 0; ct < 2; ++ct) {
            f32x4 bq4 = *(const f32x4*)(bq + wv*32 + ct*16 + quad*4);
            #pragma unroll
            for (int mt = 0; mt < 4; ++mt) {
                f32x4 qp;
                #pragma unroll
                for (int r = 0; r < 4; ++r) {
                    float q = aq[mt][ct][r] + bq4[r];
                    qp[r] = (q > 0.f) ? q + 1.f : __expf(q);
                }
                splitfrag(qp, qfh[mt][ct], qfl[mt][ct]);
            }
        }
    }

    // K + ksum
    {
        f32x4 ak[4][2];
        #pragma unroll
        for (int mt = 0; mt < 4; ++mt)
            #pragma unroll
            for (int nt = 0; nt < 2; ++nt) ak[mt][nt] = (f32x4){0.f,0.f,0.f,0.f};
        #pragma unroll
        for (int ks = 0; ks < 6; ++ks) {
            short8 ah[4], al[4];
            #pragma unroll
            for (int mt = 0; mt < 4; ++mt) {
                ah[mt] = *(const short8*)(pool + AX_H + (mt*16 + l16)*400 + ks*64 + quad*16);
                al[mt] = *(const short8*)(pool + AX_L + (mt*16 + l16)*400 + ks*64 + quad*16);
            }
            #pragma unroll
            for (int nt = 0; nt < 2; ++nt) {
                const int n = (wv*2 + nt)*16 + l16;
                short8 bh = *(const short8*)(wsp + WKH + n*KQK_ + ks*32 + quad*8);
                short8 bl = *(const short8*)(wsp + WKL + n*KQK_ + ks*32 + quad*8);
                #pragma unroll
                for (int mt = 0; mt < 4; ++mt) { MFMA3(ak[mt][nt], ah[mt], al[mt], bh, bl); }
            }
        }
        float sk[2][2] = {{0.f,0.f},{0.f,0.f}};
        #pragma unroll
        for (int nt = 0; nt < 2; ++nt) {
            float bias = bk[wv*32 + nt*16 + l16];
            #pragma unroll
            for (int mt = 0; mt < 4; ++mt) {
                f32x4 kp;
                #pragma unroll
                for (int r = 0; r < 4; ++r) {
                    float k = ak[mt][nt][r] + bias;
                    float v = (k > 0.f) ? k + 1.f : __expf(k);
                    kp[r] = v;
                    sk[mt >> 1][nt] += v;
                }
                splitfrag(kp, kfh[mt][nt], kfl[mt][nt]);
            }
        }
        #pragma unroll
        for (int tau = 0; tau < 2; ++tau)
            #pragma unroll
            for (int nt = 0; nt < 2; ++nt) {
                float s = sk[tau][nt];
                s += __shfl_xor(s, 16); s += __shfl_xor(s, 32);
                if (quad == 0) ksum[tau*128 + wv*32 + nt*16 + l16] = s;
            }
    }

    // V
    {
        f32x4 av[4][2];
        #pragma unroll
        for (int mt = 0; mt < 4; ++mt)
            #pragma unroll
            for (int nt = 0; nt < 2; ++nt) av[mt][nt] = (f32x4){0.f,0.f,0.f,0.f};
        #pragma unroll
        for (int ks = 0; ks < 4; ++ks) {
            short8 ah[4], al[4];
            #pragma unroll
            for (int mt = 0; mt < 4; ++mt) {
                ah[mt] = *(const short8*)(pool + AX_H + (mt*16 + l16)*400 + ks*64 + quad*16);
                al[mt] = *(const short8*)(pool + AX_L + (mt*16 + l16)*400 + ks*64 + quad*16);
            }
            #pragma unroll
            for (int nt = 0; nt < 2; ++nt) {
                const int n = (wv*2 + nt)*16 + l16;
                short8 bh = *(const short8*)(wsp + WVH + n*C_ + ks*32 + quad*8);
                short8 bl = *(const short8*)(wsp + WVL + n*C_ + ks*32 + quad*8);
                #pragma unroll
                for (int mt = 0; mt < 4; ++mt) { MFMA3(av[mt][nt], ah[mt], al[mt], bh, bl); }
            }
        }
        #pragma unroll
        for (int nt = 0; nt < 2; ++nt) {
            float bias = bv[wv*32 + nt*16 + l16];
            #pragma unroll
            for (int mt = 0; mt < 4; ++mt) {
                f32x4 vp;
                #pragma unroll
                for (int r = 0; r < 4; ++r) vp[r] = av[mt][nt][r] + bias;
                splitfrag(vp, vfh[mt][nt], vfl[mt][nt]);
            }
        }
    }

    // zden
    #pragma unroll
    for (int tau = 0; tau < 2; ++tau) {
        f32x4 ka0 = *(const f32x4*)(ksum + tau*128 + wv*32 + quad*4);
        f32x4 ka1 = *(const f32x4*)(ksum + tau*128 + wv*32 + 16 + quad*4);
        #pragma unroll
        for (int lt = 0; lt < 2; ++lt) {
            const int mt = tau*2 + lt;
            float p = 0.f;
            #pragma unroll
            for (int i = 0; i < 4; ++i) {
                p = fmaf(b2f((u16)(short)qfh[mt][0][i]) + b2f((u16)(short)qfl[mt][0][i]), ka0[i], p);
                p = fmaf(b2f((u16)(short)qfh[mt][1][i]) + b2f((u16)(short)qfl[mt][1][i]), ka1[i], p);
            }
            p += __shfl_xor(p, 16); p += __shfl_xor(p, 32);
            if (quad == 0) zf[tau*128 + wv*32 + lt*16 + l16] = 1.f / (p + 1e-6f);
        }
    }

    // KV
    short4v kvfh[2][2][2], kvfl[2][2][2];
    #pragma unroll
    for (int tau = 0; tau < 2; ++tau)
        #pragma unroll
        for (int dt = 0; dt < 2; ++dt)
            #pragma unroll
            for (int vt = 0; vt < 2; ++vt) {
                f32x4 kv = (f32x4){0.f,0.f,0.f,0.f};
                #pragma unroll
                for (int lt = 0; lt < 2; ++lt) {
                    const int mt = tau*2 + lt;
                    MFMA3_16(kv, kfh[mt][dt], kfl[mt][dt], vfh[mt][vt], vfl[mt][vt]);
                }
                splitfrag(kv, kvfh[tau][dt][vt], kvfl[tau][dt][vt]);
            }

    // ln1 stats
    {
        int t = tid >> 2, jj = tid & 3;
        const char* rp = pool + AX_H + t*400 + jj*64;
        float m = 0.f, s = 0.f;
        #pragma unroll
        for (int p8 = 0; p8 < 4; ++p8) {
            short8 h = *(const short8*)(rp + p8*16);
            short8 l = *(const short8*)(rp + (AX_L - AX_H) + p8*16);
            #pragma unroll
            for (int i = 0; i < 8; ++i) {
                float v = b2f((u16)h[i]) + b2f((u16)l[i]);
                m += v; s = fmaf(v, v, s);
            }
        }
        m += __shfl_xor(m, 1); s += __shfl_xor(s, 1);
        m += __shfl_xor(m, 2); s += __shfl_xor(s, 2);
        if (jj == 0) {
            float mu = m * (1.f/C_);
            stats[t]      = mu;
            stats[64 + t] = rsqrtf(s * (1.f/C_) - mu*mu + 1e-5f);
        }
    }
    __syncthreads();

    // Phase O: o1 = attn*z + ln1 residual
    f32x4 o1v[4][2];
    #pragma unroll
    for (int mt = 0; mt < 4; ++mt) {
        const int tau = mt >> 1;
        f32x4 zd4 = *(const f32x4*)(zf + tau*128 + wv*32 + (mt & 1)*16 + quad*4);
        f32x4 mu4 = *(const f32x4*)(stats + mt*16 + quad*4);
        f32x4 rs4 = *(const f32x4*)(stats + 64 + mt*16 + quad*4);
        #pragma unroll
        for (int vt = 0; vt < 2; ++vt) {
            f32x4 oa = (f32x4){0.f,0.f,0.f,0.f};
            #pragma unroll
            for (int dt = 0; dt < 2; ++dt) {
                MFMA3_16(oa, qfh[mt][dt], qfl[mt][dt], kvfh[tau][dt][vt], kvfl[tau][dt][vt]);
            }
            int ch = wv*32 + vt*16 + l16;
            float g1c = g1[ch], be1c = be1[ch];
            #pragma unroll
            for (int r = 0; r < 4; ++r) {
                int row = mt*16 + quad*4 + r;
                float xv = b2f(*(const u16*)(pool + AX_H + row*400 + ch*2))
                         + b2f(*(const u16*)(pool + AX_L + row*400 + ch*2));
                o1v[mt][vt][r] = oa[r]*zd4[r] + (xv - mu4[r])*rs4[r]*g1c + be1c;
            }
        }
    }
    __syncthreads();   // AX dead

    // X2 split planes into LDS overlay
    #pragma unroll
    for (int mt = 0; mt < 4; ++mt) {
        char* xb = pool + X2G(mt);
        #pragma unroll
        for (int vt = 0; vt < 2; ++vt) {
            int ch = wv*32 + vt*16 + l16;
            #pragma unroll
            for (int r = 0; r < 4; ++r) {
                u16 hb, lb; split2(o1v[mt][vt][r], hb, lb);
                int off = (quad*4 + r)*272 + ch*2;
                *(u16*)(xb + off)        = hb;
                *(u16*)(xb + 4352 + off) = lb;
            }
        }
    }
    __syncthreads();

    // Coalesced LDS -> global X2 (overwrites dead XT region)
    {
        u16* dst = wsp + XT + (size_t)n0 * 8192;
        #pragma unroll
        for (int i = 0; i < 8; ++i) {
            int cid = tid + i*256;              // 0..2047 short8 chunks
            int tau = cid >> 10;
            int rem = cid & 1023;
            int plane = rem >> 9;
            int rr = (rem >> 4) & 31;
            int c8 = (rem & 15) << 3;
            int grow = tau*32 + rr;
            const char* lsrc = pool + X2G(grow >> 4) + plane*4352 + (grow & 15)*272 + c8*2;
            short8 v = *reinterpret_cast<const short8*>(lsrc);
            *reinterpret_cast<short8*>(dst + (size_t)tau*8192 + plane*4096 + rr*128 + c8) = v;
        }
    }
}

// ======================= Kernel B: MLP M=64, W1/W2 panels in registers =======================
__global__ __launch_bounds__(256, 2) void mlp_mfma(
    const float* __restrict__ b2, const u16* __restrict__ wsp,
    float* __restrict__ out)
{
    extern __shared__ __align__(16) char pool[];
    float* stats = (float*)(pool + BST);
    const float* acf = (const float*)wsp;

    const int bi = blockIdx.x;                  // 0..2047
    const int j_ = ((bi & 7) << 8) | (bi >> 3); // XCD-chunked
    const int n0 = j_ * 2;                      // tiles n0, n0+1
    const int b  = n0 >> 10;
    const int hw0 = n0 & 1023;
    const int tid = threadIdx.x;
    const int lane = tid & 63, wv = tid >> 6;
    const int l16 = lane & 15, quad = lane >> 4;

    // Preload W1 panel for mh=0 (hidden under X2 staging)
    short8 w1h[4][2], w1l[4][2], w2h[4][2], w2l[4][2];
    #pragma unroll
    for (int ks = 0; ks < 4; ++ks)
        #pragma unroll
        for (int nt = 0; nt < 2; ++nt) {
            const int gn = (wv*2 + nt)*16 + l16;
            w1h[ks][nt] = *(const short8*)(wsp + W1H + gn*C_ + ks*32 + quad*8);
            w1l[ks][nt] = *(const short8*)(wsp + W1L + gn*C_ + ks*32 + quad*8);
        }

    // Stage both X2 tiles from global (coalesced)
    {
        const u16* src = wsp + XT + (size_t)n0 * 8192;
        #pragma unroll
        for (int i = 0; i < 8; ++i) {
            int cid = tid + i*256;               // 0..2047
            int tau = cid >> 10;
            int rem = cid & 1023;
            int plane = rem >> 9;
            int rr = (rem >> 4) & 31;
            int c8 = (rem & 15) << 3;
            short8 v = *reinterpret_cast<const short8*>(src + (size_t)tau*8192 + plane*4096 + rr*128 + c8);
            *reinterpret_cast<short8*>(pool + BX2 + tau*17408 + plane*8704 + rr*272 + c8*2) = v;
        }
    }
    __syncthreads();

    // ln2 stats (4 threads/row, 64 rows)
    {
        int t = tid >> 2, jj = tid & 3;
        int tau = t >> 5, rr = t & 31;
        const char* rp = pool + BX2 + tau*17408 + rr*272 + jj*64;
        float m = 0.f, s = 0.f;
        #pragma unroll
        for (int p8 = 0; p8 < 4; ++p8) {
            short8 h = *(const short8*)(rp + p8*16);
            short8 l = *(const short8*)(rp + 8704 + p8*16);
            #pragma unroll
            for (int i = 0; i < 8; ++i) {
                float v = b2f((u16)h[i]) + b2f((u16)l[i]);
                m += v; s = fmaf(v, v, s);
            }
        }
        m += __shfl_xor(m, 1); s += __shfl_xor(s, 1);
        m += __shfl_xor(m, 2); s += __shfl_xor(s, 2);
        if (jj == 0) {
            float mu = m * (1.f/C_);
            float rs = rsqrtf(s * (1.f/C_) - mu*mu + 1e-5f);
            stats[t]      = mu * rs;
            stats[64 + t] = rs;
        }
    }
    __syncthreads();

    // MLP: 4 chunks of 128 hm-channels, M=64
    f32x4 accO[4][2];   // [mt][nt]: row = mt*16+quad*4+r, out_ch = (wv*2+nt)*16+l16
    #pragma unroll
    for (int mt = 0; mt < 4; ++mt)
        #pragma unroll
        for (int nt = 0; nt < 2; ++nt) accO[mt][nt] = (f32x4){0.f,0.f,0.f,0.f};

    #pragma unroll 1
    for (int mh = 0; mh < 4; ++mh) {
        {
            f32x4 accH[4][2];
            #pragma unroll
            for (int mt = 0; mt < 4; ++mt)
                #pragma unroll
                for (int nt = 0; nt < 2; ++nt) accH[mt][nt] = (f32x4){0.f,0.f,0.f,0.f};
            #pragma unroll
            for (int ks = 0; ks < 4; ++ks) {
                short8 ah[4], al[4];
                #pragma unroll
                for (int mt = 0; mt < 4; ++mt) {
                    const char* xb = pool + BX2 + (mt >> 1)*17408 + ((mt & 1)*16 + l16)*272 + ks*64 + quad*16;
                    ah[mt] = *(const short8*)(xb);
                    al[mt] = *(const short8*)(xb + 8704);
                }
                #pragma unroll
                for (int nt = 0; nt < 2; ++nt)
                    #pragma unroll
                    for (int mt = 0; mt < 4; ++mt) { MFMA3(accH[mt][nt], w1h[ks][nt], w1l[ks][nt], ah[mt], al[mt]); }
            }
            // issue W2 panel for this chunk (hides under F epilogue)
            #pragma unroll
            for (int ks = 0; ks < 4; ++ks)
                #pragma unroll
                for (int nt = 0; nt < 2; ++nt) {
                    const int n2 = (wv*2 + nt)*16 + l16;
                    w2h[ks][nt] = *(const short8*)(wsp + W2H + n2*C4_ + mh*128 + ks*32 + quad*8);
                    w2l[ks][nt] = *(const short8*)(wsp + W2L + n2*C4_ + mh*128 + ks*32 + quad*8);
                }
            // F epilogue: folded-ln2 + fast gelu -> HM
            #pragma unroll
            for (int nt = 0; nt < 2; ++nt) {
                int base = mh*128 + (wv*2 + nt)*16 + quad*4;
                f32x4 a4 = *(const f32x4*)(acf + ACF_A + base);
                f32x4 c4 = *(const f32x4*)(acf + ACF_C + base);
                int ch0 = (wv*2 + nt)*16 + quad*4;
                #pragma unroll
                for (int mt = 0; mt < 4; ++mt) {
                    int tkg = mt*16 + l16;
                    float mrs = stats[tkg], rsv = stats[64 + tkg];
                    u16 hh[4], ll[4];
                    #pragma unroll
                    for (int r = 0; r < 4; ++r) {
                        float v = accH[mt][nt][r]*rsv - mrs*a4[r] + c4[r];
                        float ge = gelu_fast(v);
                        split2(ge, hh[r], ll[r]);
                    }
                    char* hb = pool + BHM + (mt >> 1)*17408 + ((mt & 1)*16 + l16)*272 + ch0*2;
                    *(u16x4*)(hb)        = (u16x4){hh[0],hh[1],hh[2],hh[3]};
                    *(u16x4*)(hb + 8704) = (u16x4){ll[0],ll[1],ll[2],ll[3]};
                }
            }
        }
        __syncthreads();
        {
            #pragma unroll
            for (int ks = 0; ks < 4; ++ks) {
                short8 ah[4], al[4];
                #pragma unroll
                for (int mt = 0; mt < 4; ++mt) {
                    const char* hb = pool + BHM + (mt >> 1)*17408 + ((mt & 1)*16 + l16)*272 + ks*64 + quad*16;
                    ah[mt] = *(const short8*)(hb);
                    al[mt] = *(const short8*)(hb + 8704);
                }
                #pragma unroll
                for (int nt = 0; nt < 2; ++nt)
                    #pragma unroll
                    for (int mt = 0; mt < 4; ++mt) { MFMA3(accO[mt][nt], ah[mt], al[mt], w2h[ks][nt], w2l[ks][nt]); }
            }
            // issue W1 panel for next chunk (hides under G + barrier)
            if (mh < 3) {
                #pragma unroll
                for (int ks = 0; ks < 4; ++ks)
                    #pragma unroll
                    for (int nt = 0; nt < 2; ++nt) {
                        const int gn = (mh+1)*128 + (wv*2 + nt)*16 + l16;
                        w1h[ks][nt] = *(const short8*)(wsp + W1H + gn*C_ + ks*32 + quad*8);
                        w1l[ks][nt] = *(const short8*)(wsp + W1L + gn*C_ + ks*32 + quad*8);
                    }
            }
        }
        if (mh < 3) __syncthreads();
    }

    // Epilogue: y = o1(X2 h+l) + mlp + b2, strided store (two tiles)
    {
        float* obase = out + (size_t)b * (T_*C_*HW_) + hw0;
        #pragma unroll
        for (int mt = 0; mt < 4; ++mt) {
            const int tau = mt >> 1;
            float* ob = obase + tau;
            #pragma unroll
            for (int nt = 0; nt < 2; ++nt) {
                int ch = wv*32 + nt*16 + l16;
                float b2c = b2[ch];
                #pragma unroll
                for (int r = 0; r < 4; ++r) {
                    int t = (mt & 1)*16 + quad*4 + r;
                    const char* xp = pool + BX2 + tau*17408 + t*272 + ch*2;
                    float o1 = b2f(*(const u16*)(xp)) + b2f(*(const u16*)(xp + 8704));
                    float y = o1 + accO[mt][nt][r] + b2c;
                    ob[(size_t)(t*C_ + ch) * HW_] = y;
                }
            }
        }
    }
}

extern "C" void kernel_launch(void* const* d_in, const int* in_sizes, int n_in,
                              void* d_out, int out_size, void* d_ws, size_t ws_size,
                              hipStream_t stream)
{
    const float* x   = (const float*)d_in[0];
    const float* gui = (const float*)d_in[1];
    const float* Wq  = (const float*)d_in[2];
    const float* bq  = (const float*)d_in[3];
    const float* Wk  = (const float*)d_in[4];
    const float* bk  = (const float*)d_in[5];
    const float* Wv  = (const float*)d_in[6];
    const float* bv  = (const float*)d_in[7];
    const float* g1  = (const float*)d_in[8];
    const float* be1 = (const float*)d_in[9];
    const float* g2  = (const float*)d_in[10];
    const float* be2 = (const float*)d_in[11];
    const float* W1  = (const float*)d_in[12];
    const float* b1  = (const float*)d_in[13];
    const float* W2  = (const float*)d_in[14];
    const float* b2  = (const float*)d_in[15];
    u16* wsp = (u16*)d_ws;

    int use_xt = (ws_size >= WS_NEED_BYTES) ? 1 : 0;

    prep_weights<<<dim3(802), dim3(256), 0, stream>>>(Wq, Wk, Wv, W1, W2, gui, g2, be2, b1, wsp);
    if (use_xt)
        transpose_x<<<dim3(8192), dim3(256), 0, stream>>>(x, wsp);

    (void)hipFuncSetAttribute((const void*)attn_mfma,
                              hipFuncAttributeMaxDynamicSharedMemorySize, POOLA);
    (void)hipFuncSetAttribute((const void*)mlp_mfma,
                              hipFuncAttributeMaxDynamicSharedMemorySize, POOLB);

    attn_mfma<<<dim3(2048), dim3(256), POOLA, stream>>>(
        x, bq, bk, bv, g1, be1, wsp, use_xt);
    mlp_mfma<<<dim3(2048), dim3(256), POOLB, stream>>>(
        b2, wsp, (float*)d_out);
}